// Round 1
// 255.425 us; speedup vs baseline: 1.0033x; 1.0033x over previous
//
#include <hip/hip_runtime.h>

typedef unsigned short u16;
typedef unsigned int u32;
typedef __bf16 bf16x8 __attribute__((ext_vector_type(8)));
typedef float f32x4 __attribute__((ext_vector_type(4)));
typedef unsigned short ushort8 __attribute__((ext_vector_type(8)));

__device__ __forceinline__ float bf2f(u16 b) {
    return __uint_as_float(((u32)b) << 16);
}
__device__ __forceinline__ u16 f2bf(float f) {
    u32 u = __float_as_uint(f);
    return (u16)((u + 0x7fffu + ((u >> 16) & 1u)) >> 16);
}

// fp32 canonical param block (element offsets)
#define P_CONVW 0       // 2048*4
#define P_CONVB 8192    // 2048
#define P_ALOG  10240   // 2048*16
#define P_DPAR  43008   // 2048
#define P_DTW   45056   // 2048
#define P_DTB   47104   // 2048
#define P_LNG   49152   // 2048
#define P_LNB   51200   // 2048
#define P_TOTAL 53248

// scan chunking
#define CCH 32            // chunks over L=1024
#define CT  32            // timesteps per chunk
#define CHUNKTOT 2097152  // B*CCH*16*2048
#define PSTRIDE 128       // proj row stride (N padded for MFMA)

// canon_multi segment offsets (uint2 units)
#define CV_X   524288
#define CV_W1  1572864
#define CV_TOT 2097152

struct ParamPtrs { const void* p[8]; };

// ---------------------------------------------------------------------------
// Merged canonicalization kernel:
//   blocks [0,8192)      : x / in_proj_w / out_w -> bf16 (cx|cw1|cwo)
//   blocks [8192,8400)   : fp32 param block
//   blocks [8400,8656)   : x_proj_w (33,2048) -> zero-padded bf16 (128,2048)
//   blocks [8656,8912)   : zero proj   (262144 f32, for gemm2 atomics)
//   blocks [8912,10960)  : zero d_out  (2097152 f32, for gemm3 atomics)
// ---------------------------------------------------------------------------
__global__ __launch_bounds__(256) void canon_all(ParamPtrs pp, float* __restrict__ cpar,
                                                 const void* __restrict__ sx,
                                                 const void* __restrict__ sw1,
                                                 const void* __restrict__ swo,
                                                 u16* __restrict__ cx,
                                                 const void* __restrict__ sxp,
                                                 u16* __restrict__ wpad,
                                                 float* __restrict__ proj,
                                                 float* __restrict__ dout,
                                                 const u16* __restrict__ dp) {
    const bool isbf = (dp[0] != 0);
    const int blk = blockIdx.x;
    const int tid = threadIdx.x;
    if (blk < 8192) {
        // bf16 conversion of GEMM operands (uint2 = 4 halves per thread)
        const int i = blk * 256 + tid;
        const void* src;
        int off;
        if (i < CV_X)       { src = sx;  off = i; }
        else if (i < CV_W1) { src = sw1; off = i - CV_X; }
        else                { src = swo; off = i - CV_W1; }
        if (isbf) {
            ((uint2*)cx)[i] = ((const uint2*)src)[off];
        } else {
            const float4 v = ((const float4*)src)[off];
            uint2 o;
            o.x = (u32)f2bf(v.x) | ((u32)f2bf(v.y) << 16);
            o.y = (u32)f2bf(v.z) | ((u32)f2bf(v.w) << 16);
            ((uint2*)cx)[i] = o;
        }
    } else if (blk < 8400) {
        // fp32 canonical params
        const int i = (blk - 8192) * 256 + tid;
        int seg, off;
        if (i < P_CONVB)      { seg = 0; off = i; }
        else if (i < P_ALOG)  { seg = 1; off = i - P_CONVB; }
        else if (i < P_DPAR)  { seg = 2; off = i - P_ALOG; }
        else if (i < P_DTW)   { seg = 3; off = i - P_DPAR; }
        else if (i < P_DTB)   { seg = 4; off = i - P_DTW; }
        else if (i < P_LNG)   { seg = 5; off = i - P_DTB; }
        else if (i < P_LNB)   { seg = 6; off = i - P_LNG; }
        else                  { seg = 7; off = i - P_LNB; }
        cpar[i] = isbf ? bf2f(((const u16*)pp.p[seg])[off]) : ((const float*)pp.p[seg])[off];
    } else if (blk < 8656) {
        // x_proj_w zero-padded to (128,2048) bf16
        const int i = (blk - 8400) * 256 + tid;  // over 65536
        const int idx = i * 4;
        const int row = idx >> 11;
        u16 o[4];
#pragma unroll
        for (int q = 0; q < 4; ++q) {
            float v = 0.f;
            if (row < 33)
                v = isbf ? bf2f(((const u16*)sxp)[idx + q]) : ((const float*)sxp)[idx + q];
            o[q] = f2bf(v);
        }
        *(uint2*)&wpad[idx] = *(uint2*)o;
    } else if (blk < 8912) {
        const int i = (blk - 8656) * 256 + tid;  // 65536 float4
        ((float4*)proj)[i] = make_float4(0.f, 0.f, 0.f, 0.f);
    } else {
        const int i = (blk - 8912) * 256 + tid;  // 524288 float4
        ((float4*)dout)[i] = make_float4(0.f, 0.f, 0.f, 0.f);
    }
}

// ---------------------------------------------------------------------------
// GEMM: C[M,N] = A[M, kbase:kbase+Kseg] * W[N, same]^T, bf16 in.
// Staging via __builtin_amdgcn_global_load_lds width=16 (m97 structure).
// MODE 0: bf16 store; MODE 1: f32 store at + z*M*N; MODE 2: f32 atomicAdd
// (split-K accumulate directly, destination must be pre-zeroed).
// ---------------------------------------------------------------------------
template <int MODE>
__global__ __launch_bounds__(256) void gemm_bt(const u16* __restrict__ A,
                                               const u16* __restrict__ Bw,
                                               void* __restrict__ C,
                                               int M, int N, int Kseg,
                                               int lda, int ldb) {
    const int bm = blockIdx.x;
    const int bn = blockIdx.y;
    const int kbase = blockIdx.z * Kseg;
    const int tid = threadIdx.x;
    const int lane = tid & 63;
    const int wave = tid >> 6;
    const int wm = wave >> 1, wn = wave & 1;
    const int l16 = lane & 15, quad = lane >> 4;

    __shared__ __align__(16) u16 sA[128 * 32];
    __shared__ __align__(16) u16 sB[128 * 32];

    f32x4 acc[4][4] = {};

    const int rsub = lane >> 2;          // 0..15 row within group
    const int csub = (lane & 3) * 8;     // u16 col within 32-col tile

    for (int k0 = 0; k0 < Kseg; k0 += 32) {
        const int kc = kbase + k0 + csub;
        __syncthreads();  // previous iteration's readers done
#pragma unroll
        for (int q = 0; q < 2; ++q) {
            const int g = wave + 4 * q;
            const int row = g * 16 + rsub;
            __builtin_amdgcn_global_load_lds(
                (const u32*)&A[(size_t)(bm * 128 + row) * lda + kc],
                (u32*)&sA[g * 512], 16, 0, 0);
            __builtin_amdgcn_global_load_lds(
                (const u32*)&Bw[(size_t)(bn * 128 + row) * ldb + kc],
                (u32*)&sB[g * 512], 16, 0, 0);
        }
        __syncthreads();  // drain global_load_lds (compiler emits vmcnt(0))

        bf16x8 af[4], bg[4];
#pragma unroll
        for (int t = 0; t < 4; ++t) {
            af[t] = *(const bf16x8*)&sA[(wm * 64 + t * 16 + l16) * 32 + quad * 8];
            bg[t] = *(const bf16x8*)&sB[(wn * 64 + t * 16 + l16) * 32 + quad * 8];
        }
#pragma unroll
        for (int mt = 0; mt < 4; ++mt)
#pragma unroll
            for (int nt = 0; nt < 4; ++nt)
                acc[mt][nt] = __builtin_amdgcn_mfma_f32_16x16x32_bf16(
                    af[mt], bg[nt], acc[mt][nt], 0, 0, 0);
    }

    float* Cf = (float*)C + (MODE == 1 ? (size_t)blockIdx.z * M * N : (size_t)0);
#pragma unroll
    for (int mt = 0; mt < 4; ++mt) {
#pragma unroll
        for (int r = 0; r < 4; ++r) {
            const int row = bm * 128 + wm * 64 + mt * 16 + quad * 4 + r;
#pragma unroll
            for (int nt = 0; nt < 4; ++nt) {
                const int col = bn * 128 + wn * 64 + nt * 16 + l16;
                if (MODE == 0)
                    ((u16*)C)[(size_t)row * N + col] = f2bf(acc[mt][nt][r]);
                else if (MODE == 1)
                    Cf[(size_t)row * N + col] = acc[mt][nt][r];
                else
                    unsafeAtomicAdd(&Cf[(size_t)row * N + col], acc[mt][nt][r]);
            }
        }
    }
}

// ---------------------------------------------------------------------------
// Depthwise causal conv (D_CONV=4) + SiLU, vectorized 8-wide over d.
// xz bf16 (B*L, 4096) -> xb16 bf16 (B*L, 2048).
// ---------------------------------------------------------------------------
__global__ __launch_bounds__(256) void conv_silu(const u16* __restrict__ xz,
                                                 const float* __restrict__ par,
                                                 u16* __restrict__ xb16) {
    const int idx = blockIdx.x * 256 + threadIdx.x;  // over 2*1024*256
    const int d8 = idx & 255;
    const int bl = idx >> 8;
    const int l = bl & 1023;
    const int d0 = d8 * 8;

    float acc[8];
    {
        const float4 b0 = *(const float4*)&par[P_CONVB + d0];
        const float4 b1 = *(const float4*)&par[P_CONVB + d0 + 4];
        acc[0] = b0.x; acc[1] = b0.y; acc[2] = b0.z; acc[3] = b0.w;
        acc[4] = b1.x; acc[5] = b1.y; acc[6] = b1.z; acc[7] = b1.w;
    }
    float warr[8][4];
#pragma unroll
    for (int q = 0; q < 8; ++q) {
        const float4 w = *(const float4*)&par[P_CONVW + (d0 + q) * 4];
        warr[q][0] = w.x; warr[q][1] = w.y; warr[q][2] = w.z; warr[q][3] = w.w;
    }
#pragma unroll
    for (int k = 0; k < 4; ++k) {
        const int ls = l + k - 3;
        if (ls >= 0) {
            const ushort8 xv = *(const ushort8*)&xz[(size_t)(bl + k - 3) * 4096 + d0];
#pragma unroll
            for (int q = 0; q < 8; ++q)
                acc[q] = fmaf(bf2f(xv[q]), warr[q][k], acc[q]);
        }
    }
    u16 o[8];
#pragma unroll
    for (int q = 0; q < 8; ++q) {
        const float s = acc[q] / (1.f + __expf(-acc[q]));
        o[q] = f2bf(s);
    }
    *(uint4*)&xb16[(size_t)bl * 2048 + d0] = *(uint4*)o;
}

// ---------------------------------------------------------------------------
// Chunked parallel scan, pass 1: per (b, d, chunk) compute per-n
// P = prod(dA) and S = chunk-local h (starting from 0).  16 n in registers.
// ---------------------------------------------------------------------------
__global__ __launch_bounds__(256) void scan_p1(const u16* __restrict__ xb16,
                                               const float* __restrict__ proj,
                                               const float* __restrict__ par,
                                               float* __restrict__ PS) {
    const int d = blockIdx.x * 256 + threadIdx.x;   // grid.x = 8
    const int c = blockIdx.y;                       // 0..CCH-1
    const int b = blockIdx.z;                       // 0..1
    __shared__ float sp[CT][33];
    const size_t row0 = (size_t)b * 1024 + c * CT;
    for (int f = threadIdx.x; f < CT * 33; f += 256) {
        const int i = f / 33, j = f - i * 33;
        sp[i][j] = proj[(row0 + i) * PSTRIDE + j];
    }
    float Aneg[16];
#pragma unroll
    for (int n = 0; n < 16; ++n) Aneg[n] = -__expf(par[P_ALOG + d * 16 + n]);
    const float dtw = par[P_DTW + d], dtb = par[P_DTB + d];
    __syncthreads();

    float h[16] = {}, P[16];
#pragma unroll
    for (int n = 0; n < 16; ++n) P[n] = 1.f;

    float xv = bf2f(xb16[row0 * 2048 + d]);
    for (int i = 0; i < CT; ++i) {
        const float xv_next = (i + 1 < CT) ? bf2f(xb16[(row0 + i + 1) * 2048 + d]) : 0.f;
        const float dtin = sp[i][0];
        const float darg = fmaf(dtin, dtw, dtb);
        const float dt = (darg > 20.f) ? darg : __logf(1.f + __expf(darg));
        const float xdt = xv * dt;
#pragma unroll
        for (int n = 0; n < 16; ++n) {
            const float dA = __expf(dt * Aneg[n]);
            P[n] *= dA;
            h[n] = fmaf(dA, h[n], xdt * sp[i][1 + n]);
        }
        xv = xv_next;
    }
    const size_t base = (((size_t)b * CCH + c) * 16) * 2048 + d;
#pragma unroll
    for (int n = 0; n < 16; ++n) {
        PS[base + (size_t)n * 2048] = P[n];
        PS[CHUNKTOT + base + (size_t)n * 2048] = h[n];
    }
}

// ---------------------------------------------------------------------------
// Combine: per (b,d,n), serial scan over CCH chunks: H_c = state before chunk c.
// ---------------------------------------------------------------------------
__global__ __launch_bounds__(256) void scan_comb(const float* __restrict__ PS,
                                                 float* __restrict__ H) {
    const int t = blockIdx.x * 256 + threadIdx.x;  // 65536 total
    const int d = t & 2047;
    const int n = (t >> 11) & 15;
    const int b = t >> 15;
    float h = 0.f;
#pragma unroll
    for (int c = 0; c < CCH; ++c) {
        const size_t idx = (((size_t)b * CCH + c) * 16 + n) * 2048 + d;
        H[idx] = h;
        h = fmaf(PS[idx], h, PS[CHUNKTOT + idx]);
    }
}

// ---------------------------------------------------------------------------
// Pass 2: replay each chunk from its true initial state H_c, emit y (bf16).
// ---------------------------------------------------------------------------
__global__ __launch_bounds__(256) void scan_p2(const u16* __restrict__ xb16,
                                               const float* __restrict__ proj,
                                               const float* __restrict__ par,
                                               const float* __restrict__ H,
                                               u16* __restrict__ y) {
    const int d = blockIdx.x * 256 + threadIdx.x;
    const int c = blockIdx.y;
    const int b = blockIdx.z;
    __shared__ float sp[CT][33];
    const size_t row0 = (size_t)b * 1024 + c * CT;
    for (int f = threadIdx.x; f < CT * 33; f += 256) {
        const int i = f / 33, j = f - i * 33;
        sp[i][j] = proj[(row0 + i) * PSTRIDE + j];
    }
    float Aneg[16], h[16];
    const size_t hbase = (((size_t)b * CCH + c) * 16) * 2048 + d;
#pragma unroll
    for (int n = 0; n < 16; ++n) {
        Aneg[n] = -__expf(par[P_ALOG + d * 16 + n]);
        h[n] = H[hbase + (size_t)n * 2048];
    }
    const float dtw = par[P_DTW + d], dtb = par[P_DTB + d];
    const float Dp = par[P_DPAR + d];
    __syncthreads();

    float xv = bf2f(xb16[row0 * 2048 + d]);
    for (int i = 0; i < CT; ++i) {
        const float xv_next = (i + 1 < CT) ? bf2f(xb16[(row0 + i + 1) * 2048 + d]) : 0.f;
        const float dtin = sp[i][0];
        const float darg = fmaf(dtin, dtw, dtb);
        const float dt = (darg > 20.f) ? darg : __logf(1.f + __expf(darg));
        const float xdt = xv * dt;
        float acc = 0.f;
#pragma unroll
        for (int n = 0; n < 16; ++n) {
            const float dA = __expf(dt * Aneg[n]);
            h[n] = fmaf(dA, h[n], xdt * sp[i][1 + n]);
            acc = fmaf(h[n], sp[i][17 + n], acc);
        }
        y[(row0 + i) * 2048 + d] = f2bf(fmaf(xv, Dp, acc));
        xv = xv_next;
    }
}

// ---------------------------------------------------------------------------
// LayerNorm over D_INNER + *silu(z); vectorized 8-wide contiguous per thread.
// ---------------------------------------------------------------------------
__global__ __launch_bounds__(256) void ln_silu(const u16* __restrict__ y,
                                               const u16* __restrict__ xz,
                                               const float* __restrict__ par,
                                               u16* __restrict__ yn) {
    const int row = blockIdx.x;
    const int tid = threadIdx.x;
    const int lane = tid & 63, wave = tid >> 6;
    const int d0 = tid * 8;
    const ushort8 vy = *(const ushort8*)&y[(size_t)row * 2048 + d0];
    float v[8];
    float s = 0.f, s2 = 0.f;
#pragma unroll
    for (int i = 0; i < 8; ++i) {
        v[i] = bf2f(vy[i]);
        s += v[i];
        s2 = fmaf(v[i], v[i], s2);
    }
    s += __shfl_xor(s, 1); s2 += __shfl_xor(s2, 1);
    s += __shfl_xor(s, 2); s2 += __shfl_xor(s2, 2);
    s += __shfl_xor(s, 4); s2 += __shfl_xor(s2, 4);
    s += __shfl_xor(s, 8); s2 += __shfl_xor(s2, 8);
    s += __shfl_xor(s, 16); s2 += __shfl_xor(s2, 16);
    s += __shfl_xor(s, 32); s2 += __shfl_xor(s2, 32);
    __shared__ float rs[4], rs2[4];
    if (lane == 0) { rs[wave] = s; rs2[wave] = s2; }
    __syncthreads();
    const float ts = rs[0] + rs[1] + rs[2] + rs[3];
    const float ts2 = rs2[0] + rs2[1] + rs2[2] + rs2[3];
    const float mu = ts * (1.f / 2048.f);
    const float var = ts2 * (1.f / 2048.f) - mu * mu;
    const float rstd = rsqrtf(var + 1e-5f);

    const ushort8 vz = *(const ushort8*)&xz[(size_t)row * 4096 + 2048 + d0];
    float g[8], bb[8];
    {
        const float4 g0 = *(const float4*)&par[P_LNG + d0];
        const float4 g1 = *(const float4*)&par[P_LNG + d0 + 4];
        g[0] = g0.x; g[1] = g0.y; g[2] = g0.z; g[3] = g0.w;
        g[4] = g1.x; g[5] = g1.y; g[6] = g1.z; g[7] = g1.w;
        const float4 b0 = *(const float4*)&par[P_LNB + d0];
        const float4 b1 = *(const float4*)&par[P_LNB + d0 + 4];
        bb[0] = b0.x; bb[1] = b0.y; bb[2] = b0.z; bb[3] = b0.w;
        bb[4] = b1.x; bb[5] = b1.y; bb[6] = b1.z; bb[7] = b1.w;
    }
    u16 o[8];
#pragma unroll
    for (int i = 0; i < 8; ++i) {
        float t = (v[i] - mu) * rstd * g[i] + bb[i];
        const float z = bf2f(vz[i]);
        t *= z / (1.f + __expf(-z));
        o[i] = f2bf(t);
    }
    *(uint4*)&yn[(size_t)row * 2048 + d0] = *(uint4*)o;
}

// ---------------------------------------------------------------------------
extern "C" void kernel_launch(void* const* d_in, const int* in_sizes, int n_in,
                              void* d_out, int out_size, void* d_ws, size_t ws_size,
                              hipStream_t stream) {
    const void* x         = d_in[0];   // (2,1024,1024) fp32
    const void* in_proj_w = d_in[1];
    const void* conv_w    = d_in[2];
    const void* conv_b    = d_in[3];
    const void* x_proj_w  = d_in[4];
    const void* A_log     = d_in[5];
    const void* D_param   = d_in[6];
    const void* dt_w      = d_in[7];
    const void* dt_b      = d_in[8];
    const void* out_w     = d_in[9];
    const void* ln_g      = d_in[10];
    const void* ln_b      = d_in[11];
    const u16* dp = (const u16*)D_param;

    // workspace layout
    float* cpar = (float*)d_ws;              // 53,248 f32
    u16* cx     = (u16*)(cpar + P_TOTAL);    // 2,097,152 u16 (4 MB)
    u16* cw1    = cx + 2097152;              // 4,194,304 u16 (8 MB)
    u16* cwo    = cw1 + 4194304;             // 2,097,152 u16 (4 MB)
    u16* xz     = cwo + 2097152;             // 8,388,608 u16 (16 MB)
    u16* xb16   = xz + 8388608;              // 4,194,304 u16 (8 MB)
    u16* y      = xb16 + 4194304;            // 4,194,304 u16 (8 MB)
    u16* wpad   = y + 4194304;               // 262,144 u16   (0.5 MB)
    float* proj = (float*)(wpad + 262144);   // 2048*128 f32  (1 MB)
    float* PS   = proj + 262144;             // 2*CHUNKTOT f32 (16 MB)
    float* H    = PS + 2 * CHUNKTOT;         // CHUNKTOT f32   (8 MB)
    u16* yn     = xb16;                      // xb16 dead after scan_p2

    // 0. canonicalize params + convert GEMM operands + zero atomic targets
    ParamPtrs pp;
    pp.p[0] = conv_w; pp.p[1] = conv_b; pp.p[2] = A_log; pp.p[3] = D_param;
    pp.p[4] = dt_w;   pp.p[5] = dt_b;   pp.p[6] = ln_g;  pp.p[7] = ln_b;
    canon_all<<<10960, 256, 0, stream>>>(pp, cpar, x, in_proj_w, out_w, cx,
                                         x_proj_w, wpad, proj, (float*)d_out, dp);

    // 1. in_proj: xz = x @ in_proj_w^T   (M=2048, N=4096, K=1024), bf16 out
    gemm_bt<0><<<dim3(16, 32, 1), 256, 0, stream>>>(cx, cw1, xz, 2048, 4096, 1024, 1024, 1024);
    // 2. causal conv4 + silu -> bf16 (8-wide vectorized)
    conv_silu<<<2048, 256, 0, stream>>>(xz, cpar, xb16);
    // 3. x_proj GEMM, split-K 8x, atomic f32 accumulate into proj
    gemm_bt<2><<<dim3(16, 1, 8), 256, 0, stream>>>(xb16, wpad, proj, 2048, 128, 256, 2048, 2048);
    // 4. chunked parallel scan (CCH=32 chunks of CT=32)
    scan_p1<<<dim3(8, CCH, 2), 256, 0, stream>>>(xb16, proj, cpar, PS);
    scan_comb<<<256, 256, 0, stream>>>(PS, H);
    scan_p2<<<dim3(8, CCH, 2), 256, 0, stream>>>(xb16, proj, cpar, H, y);
    // 5. layernorm + silu(z) gate (yn overlays xb16)
    ln_silu<<<2048, 256, 0, stream>>>(y, xz, cpar, yn);
    // 6. out proj, split-K 2x, atomic f32 accumulate into d_out
    gemm_bt<2><<<dim3(16, 8, 2), 256, 0, stream>>>(yn, cwo, (float*)d_out, 2048, 1024, 1024, 2048, 2048);
}

// Round 2
// 241.481 us; speedup vs baseline: 1.0613x; 1.0577x over previous
//
#include <hip/hip_runtime.h>

typedef unsigned short u16;
typedef unsigned int u32;
typedef __bf16 bf16x8 __attribute__((ext_vector_type(8)));
typedef float f32x4 __attribute__((ext_vector_type(4)));
typedef unsigned short ushort8 __attribute__((ext_vector_type(8)));

__device__ __forceinline__ float bf2f(u16 b) {
    return __uint_as_float(((u32)b) << 16);
}
__device__ __forceinline__ u16 f2bf(float f) {
    u32 u = __float_as_uint(f);
    return (u16)((u + 0x7fffu + ((u >> 16) & 1u)) >> 16);
}

// fp32 canonical param block (element offsets)
#define P_CONVW 0       // 2048*4
#define P_CONVB 8192    // 2048
#define P_ALOG  10240   // 2048*16
#define P_DPAR  43008   // 2048
#define P_DTW   45056   // 2048
#define P_DTB   47104   // 2048
#define P_LNG   49152   // 2048
#define P_LNB   51200   // 2048
#define P_TOTAL 53248

// scan chunking
#define CCH 32            // chunks over L=1024
#define CT  32            // timesteps per chunk
#define CHUNKTOT 2097152  // B*CCH*16*2048
#define PSTRIDE 128       // proj row stride (N padded for MFMA)

// canon segment offsets (uint2 units)
#define CV_X   524288
#define CV_W1  1572864
#define CV_TOT 2097152

struct ParamPtrs { const void* p[8]; };

// ---------------------------------------------------------------------------
// Merged canonicalization kernel:
//   blocks [0,8192)      : x / in_proj_w / out_w -> bf16 (cx|cw1|cwo)
//   blocks [8192,8400)   : fp32 param block
//   blocks [8400,8656)   : x_proj_w (33,2048) -> zero-padded bf16 (128,2048)
// ---------------------------------------------------------------------------
__global__ __launch_bounds__(256) void canon_all(ParamPtrs pp, float* __restrict__ cpar,
                                                 const void* __restrict__ sx,
                                                 const void* __restrict__ sw1,
                                                 const void* __restrict__ swo,
                                                 u16* __restrict__ cx,
                                                 const void* __restrict__ sxp,
                                                 u16* __restrict__ wpad,
                                                 const u16* __restrict__ dp) {
    const bool isbf = (dp[0] != 0);
    const int blk = blockIdx.x;
    const int tid = threadIdx.x;
    if (blk < 8192) {
        const int i = blk * 256 + tid;
        const void* src;
        int off;
        if (i < CV_X)       { src = sx;  off = i; }
        else if (i < CV_W1) { src = sw1; off = i - CV_X; }
        else                { src = swo; off = i - CV_W1; }
        if (isbf) {
            ((uint2*)cx)[i] = ((const uint2*)src)[off];
        } else {
            const float4 v = ((const float4*)src)[off];
            uint2 o;
            o.x = (u32)f2bf(v.x) | ((u32)f2bf(v.y) << 16);
            o.y = (u32)f2bf(v.z) | ((u32)f2bf(v.w) << 16);
            ((uint2*)cx)[i] = o;
        }
    } else if (blk < 8400) {
        const int i = (blk - 8192) * 256 + tid;
        int seg, off;
        if (i < P_CONVB)      { seg = 0; off = i; }
        else if (i < P_ALOG)  { seg = 1; off = i - P_CONVB; }
        else if (i < P_DPAR)  { seg = 2; off = i - P_ALOG; }
        else if (i < P_DTW)   { seg = 3; off = i - P_DPAR; }
        else if (i < P_DTB)   { seg = 4; off = i - P_DTW; }
        else if (i < P_LNG)   { seg = 5; off = i - P_DTB; }
        else if (i < P_LNB)   { seg = 6; off = i - P_LNG; }
        else                  { seg = 7; off = i - P_LNB; }
        cpar[i] = isbf ? bf2f(((const u16*)pp.p[seg])[off]) : ((const float*)pp.p[seg])[off];
    } else {
        const int i = (blk - 8400) * 256 + tid;  // over 65536
        const int idx = i * 4;
        const int row = idx >> 11;
        u16 o[4];
#pragma unroll
        for (int q = 0; q < 4; ++q) {
            float v = 0.f;
            if (row < 33)
                v = isbf ? bf2f(((const u16*)sxp)[idx + q]) : ((const float*)sxp)[idx + q];
            o[q] = f2bf(v);
        }
        *(uint2*)&wpad[idx] = *(uint2*)o;
    }
}

// ---------------------------------------------------------------------------
// NEW GEMM: C[M,N] = A[M,Kseg@z] * W[N,Kseg@z]^T, bf16 in.
// BM=128, BN=256, BK=64, 512 threads (8 waves, 2Mx4N).
// Triple-buffered LDS (144 KiB), counted vmcnt(6) (never 0 in main loop),
// raw s_barrier, XOR-swizzled LDS layout (byte ^= (row&7)<<4) realized via
// pre-swizzled global source (global_load_lds writes linear), setprio around
// MFMA clusters.  MODE 0: bf16 store; MODE 1: f32 store at + z*M*N.
// ---------------------------------------------------------------------------
__device__ __forceinline__ bf16x8 lds_frag(const char* smem, u32 base, int row, int kk,
                                           int quad, u32 xorv) {
    const u32 addr = (base + (u32)(row * 128 + kk * 64 + quad * 16)) ^ xorv;
    return *(const bf16x8*)(smem + addr);
}

template <int MODE>
__global__ __launch_bounds__(512, 2) void gemm8(const u16* __restrict__ A,
                                                const u16* __restrict__ Bw,
                                                void* __restrict__ C,
                                                int M, int N, int Kseg,
                                                int lda, int ldb) {
    extern __shared__ char smem[];
    const int bm = blockIdx.x, bn = blockIdx.y;
    const int kbase = blockIdx.z * Kseg;
    const int tid = threadIdx.x;
    const int lane = tid & 63, wave = tid >> 6;
    const int wm = wave >> 2, wn = wave & 3;
    const int l16 = lane & 15, quad = lane >> 4;
    const int NT = Kseg >> 6;
    const u32 xorv = (u32)((l16 & 7) << 4);

    // staging geometry: one global_load_lds issue = 512 thr x 16B = 8 KB = 64 rows.
    // wave writes rows [wave*8, wave*8+8) of the issue; lane covers phys chunk lane&7.
    // Pre-swizzle: logical chunk = phys ^ (row&7)  (row&7 == (lane>>3)&7).
    const int rIss = wave * 8 + (lane >> 3);
    const int logC = (lane & 7) ^ ((lane >> 3) & 7);
    size_t aSrc[2], bSrc[4];
#pragma unroll
    for (int j = 0; j < 2; ++j)
        aSrc[j] = (size_t)(bm * 128 + j * 64 + rIss) * lda + logC * 8 + kbase;
#pragma unroll
    for (int j = 0; j < 4; ++j)
        bSrc[j] = (size_t)(bn * 256 + j * 64 + rIss) * ldb + logC * 8 + kbase;
    const u32 ldsW = (u32)(wave * 1024);

#define SG_A(slot, j, kel) __builtin_amdgcn_global_load_lds( \
        (const u32*)(A + aSrc[j] + (kel)), (u32*)(smem + (slot) + (j) * 8192 + ldsW), 16, 0, 0)
#define SG_B(slot, j, kel) __builtin_amdgcn_global_load_lds( \
        (const u32*)(Bw + bSrc[j] + (kel)), (u32*)(smem + (slot) + (j) * 8192 + ldsW), 16, 0, 0)

    // slot base byte offsets: A slots 16KB x3, B slots 32KB x3
    const u32 sA0 = 0, sA1 = 16384, sA2 = 32768;
    const u32 sB0 = 49152, sB1 = 81920, sB2 = 114688;

    // prologue: stage K-tile 0 and 1
    SG_A(sA0, 0, 0); SG_A(sA0, 1, 0);
    SG_B(sB0, 0, 0); SG_B(sB0, 1, 0); SG_B(sB0, 2, 0); SG_B(sB0, 3, 0);
    SG_A(sA1, 0, 64); SG_A(sA1, 1, 64);
    SG_B(sB1, 0, 64); SG_B(sB1, 1, 64); SG_B(sB1, 2, 64); SG_B(sB1, 3, 64);
    asm volatile("s_waitcnt vmcnt(6)" ::: "memory");  // K0 complete, K1 may fly
    __builtin_amdgcn_s_barrier();
    __builtin_amdgcn_sched_barrier(0);

    u32 curA = sA0, nxtA = sA1, stgA = sA2;
    u32 curB = sB0, nxtB = sB1, stgB = sB2;
    int kStage = 128;

    f32x4 acc[4][4] = {};
    bf16x8 a[4][2], b[4][2];

    for (int t = 0; t < NT; ++t) {
        const bool doStage = (t + 2) < NT;
        // ---- phase 0: read A (8 b128) + B-low (4 b128); stage 3; 16 MFMA ----
#pragma unroll
        for (int mt = 0; mt < 4; ++mt)
#pragma unroll
            for (int kk = 0; kk < 2; ++kk)
                a[mt][kk] = lds_frag(smem, curA, wm * 64 + mt * 16 + l16, kk, quad, xorv);
#pragma unroll
        for (int nt = 0; nt < 2; ++nt)
#pragma unroll
            for (int kk = 0; kk < 2; ++kk)
                b[nt][kk] = lds_frag(smem, curB, wn * 64 + nt * 16 + l16, kk, quad, xorv);
        if (doStage) { SG_A(stgA, 0, kStage); SG_A(stgA, 1, kStage); SG_B(stgB, 0, kStage); }
        __builtin_amdgcn_s_setprio(1);
#pragma unroll
        for (int mt = 0; mt < 4; ++mt)
#pragma unroll
            for (int nt = 0; nt < 2; ++nt)
#pragma unroll
                for (int kk = 0; kk < 2; ++kk)
                    acc[mt][nt] = __builtin_amdgcn_mfma_f32_16x16x32_bf16(
                        a[mt][kk], b[nt][kk], acc[mt][nt], 0, 0, 0);
        __builtin_amdgcn_s_setprio(0);
        // ---- phase 1: read B-high (4 b128); stage 3; 16 MFMA ----
#pragma unroll
        for (int nt = 2; nt < 4; ++nt)
#pragma unroll
            for (int kk = 0; kk < 2; ++kk)
                b[nt][kk] = lds_frag(smem, curB, wn * 64 + nt * 16 + l16, kk, quad, xorv);
        if (doStage) { SG_B(stgB, 1, kStage); SG_B(stgB, 2, kStage); SG_B(stgB, 3, kStage); }
        __builtin_amdgcn_s_setprio(1);
#pragma unroll
        for (int mt = 0; mt < 4; ++mt)
#pragma unroll
            for (int nt = 2; nt < 4; ++nt)
#pragma unroll
                for (int kk = 0; kk < 2; ++kk)
                    acc[mt][nt] = __builtin_amdgcn_mfma_f32_16x16x32_bf16(
                        a[mt][kk], b[nt][kk], acc[mt][nt], 0, 0, 0);
        __builtin_amdgcn_s_setprio(0);
        // ---- boundary: certify K(t+1); rotate slots ----
        if (t < NT - 1) {
            if (doStage) asm volatile("s_waitcnt vmcnt(6)" ::: "memory");
            else         asm volatile("s_waitcnt vmcnt(0)" ::: "memory");
            __builtin_amdgcn_s_barrier();
            __builtin_amdgcn_sched_barrier(0);
            u32 tA = curA; curA = nxtA; nxtA = stgA; stgA = tA;
            u32 tB = curB; curB = nxtB; nxtB = stgB; stgB = tB;
            kStage += 64;
        }
    }
#undef SG_A
#undef SG_B

    float* Cf = (float*)C + (MODE == 1 ? (size_t)blockIdx.z * M * N : (size_t)0);
#pragma unroll
    for (int mt = 0; mt < 4; ++mt) {
#pragma unroll
        for (int r = 0; r < 4; ++r) {
            const int row = bm * 128 + wm * 64 + mt * 16 + quad * 4 + r;
#pragma unroll
            for (int nt = 0; nt < 4; ++nt) {
                const int col = bn * 256 + wn * 64 + nt * 16 + l16;
                if (MODE == 0)
                    ((u16*)C)[(size_t)row * N + col] = f2bf(acc[mt][nt][r]);
                else
                    Cf[(size_t)row * N + col] = acc[mt][nt][r];
            }
        }
    }
}

// ---------------------------------------------------------------------------
// OLD GEMM (m97 structure), kept for the skinny x_proj (N=128).
// MODE 0: bf16 store; MODE 1: f32 store at + z*M*N.
// ---------------------------------------------------------------------------
template <int MODE>
__global__ __launch_bounds__(256) void gemm_bt(const u16* __restrict__ A,
                                               const u16* __restrict__ Bw,
                                               void* __restrict__ C,
                                               int M, int N, int Kseg,
                                               int lda, int ldb) {
    const int bm = blockIdx.x;
    const int bn = blockIdx.y;
    const int kbase = blockIdx.z * Kseg;
    const int tid = threadIdx.x;
    const int lane = tid & 63;
    const int wave = tid >> 6;
    const int wm = wave >> 1, wn = wave & 1;
    const int l16 = lane & 15, quad = lane >> 4;

    __shared__ __align__(16) u16 sA[128 * 32];
    __shared__ __align__(16) u16 sB[128 * 32];

    f32x4 acc[4][4] = {};

    const int rsub = lane >> 2;
    const int csub = (lane & 3) * 8;

    for (int k0 = 0; k0 < Kseg; k0 += 32) {
        const int kc = kbase + k0 + csub;
        __syncthreads();
#pragma unroll
        for (int q = 0; q < 2; ++q) {
            const int g = wave + 4 * q;
            const int row = g * 16 + rsub;
            __builtin_amdgcn_global_load_lds(
                (const u32*)&A[(size_t)(bm * 128 + row) * lda + kc],
                (u32*)&sA[g * 512], 16, 0, 0);
            __builtin_amdgcn_global_load_lds(
                (const u32*)&Bw[(size_t)(bn * 128 + row) * ldb + kc],
                (u32*)&sB[g * 512], 16, 0, 0);
        }
        __syncthreads();

        bf16x8 af[4], bg[4];
#pragma unroll
        for (int t = 0; t < 4; ++t) {
            af[t] = *(const bf16x8*)&sA[(wm * 64 + t * 16 + l16) * 32 + quad * 8];
            bg[t] = *(const bf16x8*)&sB[(wn * 64 + t * 16 + l16) * 32 + quad * 8];
        }
#pragma unroll
        for (int mt = 0; mt < 4; ++mt)
#pragma unroll
            for (int nt = 0; nt < 4; ++nt)
                acc[mt][nt] = __builtin_amdgcn_mfma_f32_16x16x32_bf16(
                    af[mt], bg[nt], acc[mt][nt], 0, 0, 0);
    }

    float* Cf = (float*)C + (MODE == 1 ? (size_t)blockIdx.z * M * N : (size_t)0);
#pragma unroll
    for (int mt = 0; mt < 4; ++mt) {
#pragma unroll
        for (int r = 0; r < 4; ++r) {
            const int row = bm * 128 + wm * 64 + mt * 16 + quad * 4 + r;
#pragma unroll
            for (int nt = 0; nt < 4; ++nt) {
                const int col = bn * 128 + wn * 64 + nt * 16 + l16;
                if (MODE == 0)
                    ((u16*)C)[(size_t)row * N + col] = f2bf(acc[mt][nt][r]);
                else
                    Cf[(size_t)row * N + col] = acc[mt][nt][r];
            }
        }
    }
}

// sum P parts of length n (floats), float4-vectorized
__global__ __launch_bounds__(256) void reduce_parts(const float* __restrict__ src,
                                                    float* __restrict__ dst,
                                                    int n4, int parts) {
    const int i = blockIdx.x * 256 + threadIdx.x;
    if (i >= n4) return;
    float4 s = ((const float4*)src)[i];
    for (int p = 1; p < parts; ++p) {
        const float4 v = ((const float4*)src)[(size_t)p * n4 + i];
        s.x += v.x; s.y += v.y; s.z += v.z; s.w += v.w;
    }
    ((float4*)dst)[i] = s;
}

// ---------------------------------------------------------------------------
// Depthwise causal conv (D_CONV=4) + SiLU, vectorized 8-wide over d.
// ---------------------------------------------------------------------------
__global__ __launch_bounds__(256) void conv_silu(const u16* __restrict__ xz,
                                                 const float* __restrict__ par,
                                                 u16* __restrict__ xb16) {
    const int idx = blockIdx.x * 256 + threadIdx.x;  // over 2*1024*256
    const int d8 = idx & 255;
    const int bl = idx >> 8;
    const int l = bl & 1023;
    const int d0 = d8 * 8;

    float acc[8];
    {
        const float4 b0 = *(const float4*)&par[P_CONVB + d0];
        const float4 b1 = *(const float4*)&par[P_CONVB + d0 + 4];
        acc[0] = b0.x; acc[1] = b0.y; acc[2] = b0.z; acc[3] = b0.w;
        acc[4] = b1.x; acc[5] = b1.y; acc[6] = b1.z; acc[7] = b1.w;
    }
    float warr[8][4];
#pragma unroll
    for (int q = 0; q < 8; ++q) {
        const float4 w = *(const float4*)&par[P_CONVW + (d0 + q) * 4];
        warr[q][0] = w.x; warr[q][1] = w.y; warr[q][2] = w.z; warr[q][3] = w.w;
    }
#pragma unroll
    for (int k = 0; k < 4; ++k) {
        const int ls = l + k - 3;
        if (ls >= 0) {
            const ushort8 xv = *(const ushort8*)&xz[(size_t)(bl + k - 3) * 4096 + d0];
#pragma unroll
            for (int q = 0; q < 8; ++q)
                acc[q] = fmaf(bf2f(xv[q]), warr[q][k], acc[q]);
        }
    }
    u16 o[8];
#pragma unroll
    for (int q = 0; q < 8; ++q) {
        const float s = acc[q] / (1.f + __expf(-acc[q]));
        o[q] = f2bf(s);
    }
    *(uint4*)&xb16[(size_t)bl * 2048 + d0] = *(uint4*)o;
}

// ---------------------------------------------------------------------------
// Chunked parallel scan, pass 1.
// ---------------------------------------------------------------------------
__global__ __launch_bounds__(256) void scan_p1(const u16* __restrict__ xb16,
                                               const float* __restrict__ proj,
                                               const float* __restrict__ par,
                                               float* __restrict__ PS) {
    const int d = blockIdx.x * 256 + threadIdx.x;
    const int c = blockIdx.y;
    const int b = blockIdx.z;
    __shared__ float sp[CT][33];
    const size_t row0 = (size_t)b * 1024 + c * CT;
    for (int f = threadIdx.x; f < CT * 33; f += 256) {
        const int i = f / 33, j = f - i * 33;
        sp[i][j] = proj[(row0 + i) * PSTRIDE + j];
    }
    float Aneg[16];
#pragma unroll
    for (int n = 0; n < 16; ++n) Aneg[n] = -__expf(par[P_ALOG + d * 16 + n]);
    const float dtw = par[P_DTW + d], dtb = par[P_DTB + d];
    __syncthreads();

    float h[16] = {}, P[16];
#pragma unroll
    for (int n = 0; n < 16; ++n) P[n] = 1.f;

    float xv = bf2f(xb16[row0 * 2048 + d]);
    for (int i = 0; i < CT; ++i) {
        const float xv_next = (i + 1 < CT) ? bf2f(xb16[(row0 + i + 1) * 2048 + d]) : 0.f;
        const float dtin = sp[i][0];
        const float darg = fmaf(dtin, dtw, dtb);
        const float dt = (darg > 20.f) ? darg : __logf(1.f + __expf(darg));
        const float xdt = xv * dt;
#pragma unroll
        for (int n = 0; n < 16; ++n) {
            const float dA = __expf(dt * Aneg[n]);
            P[n] *= dA;
            h[n] = fmaf(dA, h[n], xdt * sp[i][1 + n]);
        }
        xv = xv_next;
    }
    const size_t base = (((size_t)b * CCH + c) * 16) * 2048 + d;
#pragma unroll
    for (int n = 0; n < 16; ++n) {
        PS[base + (size_t)n * 2048] = P[n];
        PS[CHUNKTOT + base + (size_t)n * 2048] = h[n];
    }
}

// ---------------------------------------------------------------------------
// Combine: per (b,d,n), serial scan over CCH chunks.
// ---------------------------------------------------------------------------
__global__ __launch_bounds__(256) void scan_comb(const float* __restrict__ PS,
                                                 float* __restrict__ H) {
    const int t = blockIdx.x * 256 + threadIdx.x;  // 65536 total
    const int d = t & 2047;
    const int n = (t >> 11) & 15;
    const int b = t >> 15;
    float h = 0.f;
#pragma unroll
    for (int c = 0; c < CCH; ++c) {
        const size_t idx = (((size_t)b * CCH + c) * 16 + n) * 2048 + d;
        H[idx] = h;
        h = fmaf(PS[idx], h, PS[CHUNKTOT + idx]);
    }
}

// ---------------------------------------------------------------------------
// Pass 2: replay each chunk from its true initial state H_c, emit y (bf16).
// ---------------------------------------------------------------------------
__global__ __launch_bounds__(256) void scan_p2(const u16* __restrict__ xb16,
                                               const float* __restrict__ proj,
                                               const float* __restrict__ par,
                                               const float* __restrict__ H,
                                               u16* __restrict__ y) {
    const int d = blockIdx.x * 256 + threadIdx.x;
    const int c = blockIdx.y;
    const int b = blockIdx.z;
    __shared__ float sp[CT][33];
    const size_t row0 = (size_t)b * 1024 + c * CT;
    for (int f = threadIdx.x; f < CT * 33; f += 256) {
        const int i = f / 33, j = f - i * 33;
        sp[i][j] = proj[(row0 + i) * PSTRIDE + j];
    }
    float Aneg[16], h[16];
    const size_t hbase = (((size_t)b * CCH + c) * 16) * 2048 + d;
#pragma unroll
    for (int n = 0; n < 16; ++n) {
        Aneg[n] = -__expf(par[P_ALOG + d * 16 + n]);
        h[n] = H[hbase + (size_t)n * 2048];
    }
    const float dtw = par[P_DTW + d], dtb = par[P_DTB + d];
    const float Dp = par[P_DPAR + d];
    __syncthreads();

    float xv = bf2f(xb16[row0 * 2048 + d]);
    for (int i = 0; i < CT; ++i) {
        const float xv_next = (i + 1 < CT) ? bf2f(xb16[(row0 + i + 1) * 2048 + d]) : 0.f;
        const float dtin = sp[i][0];
        const float darg = fmaf(dtin, dtw, dtb);
        const float dt = (darg > 20.f) ? darg : __logf(1.f + __expf(darg));
        const float xdt = xv * dt;
        float acc = 0.f;
#pragma unroll
        for (int n = 0; n < 16; ++n) {
            const float dA = __expf(dt * Aneg[n]);
            h[n] = fmaf(dA, h[n], xdt * sp[i][1 + n]);
            acc = fmaf(h[n], sp[i][17 + n], acc);
        }
        y[(row0 + i) * 2048 + d] = f2bf(fmaf(xv, Dp, acc));
        xv = xv_next;
    }
}

// ---------------------------------------------------------------------------
// LayerNorm over D_INNER + *silu(z); vectorized 8-wide contiguous per thread.
// ---------------------------------------------------------------------------
__global__ __launch_bounds__(256) void ln_silu(const u16* __restrict__ y,
                                               const u16* __restrict__ xz,
                                               const float* __restrict__ par,
                                               u16* __restrict__ yn) {
    const int row = blockIdx.x;
    const int tid = threadIdx.x;
    const int lane = tid & 63, wave = tid >> 6;
    const int d0 = tid * 8;
    const ushort8 vy = *(const ushort8*)&y[(size_t)row * 2048 + d0];
    float v[8];
    float s = 0.f, s2 = 0.f;
#pragma unroll
    for (int i = 0; i < 8; ++i) {
        v[i] = bf2f(vy[i]);
        s += v[i];
        s2 = fmaf(v[i], v[i], s2);
    }
    s += __shfl_xor(s, 1); s2 += __shfl_xor(s2, 1);
    s += __shfl_xor(s, 2); s2 += __shfl_xor(s2, 2);
    s += __shfl_xor(s, 4); s2 += __shfl_xor(s2, 4);
    s += __shfl_xor(s, 8); s2 += __shfl_xor(s2, 8);
    s += __shfl_xor(s, 16); s2 += __shfl_xor(s2, 16);
    s += __shfl_xor(s, 32); s2 += __shfl_xor(s2, 32);
    __shared__ float rs[4], rs2[4];
    if (lane == 0) { rs[wave] = s; rs2[wave] = s2; }
    __syncthreads();
    const float ts = rs[0] + rs[1] + rs[2] + rs[3];
    const float ts2 = rs2[0] + rs2[1] + rs2[2] + rs2[3];
    const float mu = ts * (1.f / 2048.f);
    const float var = ts2 * (1.f / 2048.f) - mu * mu;
    const float rstd = rsqrtf(var + 1e-5f);

    const ushort8 vz = *(const ushort8*)&xz[(size_t)row * 4096 + 2048 + d0];
    float g[8], bb[8];
    {
        const float4 g0 = *(const float4*)&par[P_LNG + d0];
        const float4 g1 = *(const float4*)&par[P_LNG + d0 + 4];
        g[0] = g0.x; g[1] = g0.y; g[2] = g0.z; g[3] = g0.w;
        g[4] = g1.x; g[5] = g1.y; g[6] = g1.z; g[7] = g1.w;
        const float4 b0 = *(const float4*)&par[P_LNB + d0];
        const float4 b1 = *(const float4*)&par[P_LNB + d0 + 4];
        bb[0] = b0.x; bb[1] = b0.y; bb[2] = b0.z; bb[3] = b0.w;
        bb[4] = b1.x; bb[5] = b1.y; bb[6] = b1.z; bb[7] = b1.w;
    }
    u16 o[8];
#pragma unroll
    for (int i = 0; i < 8; ++i) {
        float t = (v[i] - mu) * rstd * g[i] + bb[i];
        const float z = bf2f(vz[i]);
        t *= z / (1.f + __expf(-z));
        o[i] = f2bf(t);
    }
    *(uint4*)&yn[(size_t)row * 2048 + d0] = *(uint4*)o;
}

// ---------------------------------------------------------------------------
extern "C" void kernel_launch(void* const* d_in, const int* in_sizes, int n_in,
                              void* d_out, int out_size, void* d_ws, size_t ws_size,
                              hipStream_t stream) {
    const void* x         = d_in[0];   // (2,1024,1024) fp32
    const void* in_proj_w = d_in[1];
    const void* conv_w    = d_in[2];
    const void* conv_b    = d_in[3];
    const void* x_proj_w  = d_in[4];
    const void* A_log     = d_in[5];
    const void* D_param   = d_in[6];
    const void* dt_w      = d_in[7];
    const void* dt_b      = d_in[8];
    const void* out_w     = d_in[9];
    const void* ln_g      = d_in[10];
    const void* ln_b      = d_in[11];
    const u16* dp = (const u16*)D_param;

    // workspace layout
    float* cpar = (float*)d_ws;              // 53,248 f32
    u16* cx     = (u16*)(cpar + P_TOTAL);    // 2,097,152 u16 (4 MB)
    u16* cw1    = cx + 2097152;              // 4,194,304 u16 (8 MB)
    u16* cwo    = cw1 + 4194304;             // 2,097,152 u16 (4 MB)
    u16* xz     = cwo + 2097152;             // 8,388,608 u16 (16 MB)
    u16* xb16   = xz + 8388608;              // 4,194,304 u16 (8 MB)
    u16* y      = xb16 + 4194304;            // 4,194,304 u16 (8 MB)
    u16* wpad   = y + 4194304;               // 262,144 u16   (0.5 MB)
    float* proj = (float*)(wpad + 262144);   // 2048*128 f32  (1 MB)
    float* PS   = proj + 262144;             // 2*CHUNKTOT f32 (16 MB)
    float* H    = PS + 2 * CHUNKTOT;         // CHUNKTOT f32   (8 MB)
    float* gpart = H + CHUNKTOT;             // 4*2048*1024 f32 (32 MB)
    // overlays:
    float* xpart = (float*)cx;               // 8*2048*128 f32 (8 MB) — after gemm1
    u16* yn      = xb16;                     // xb16 dead after scan_p2

    // raise dynamic-LDS cap for the 144 KiB GEMM (host-side, graph-safe)
    static bool attrSet = false;
    if (!attrSet) {
        hipFuncSetAttribute(reinterpret_cast<const void*>(&gemm8<0>),
                            hipFuncAttributeMaxDynamicSharedMemorySize, 147456);
        hipFuncSetAttribute(reinterpret_cast<const void*>(&gemm8<1>),
                            hipFuncAttributeMaxDynamicSharedMemorySize, 147456);
        attrSet = true;
    }

    // 0. canonicalize params + convert GEMM operands to bf16
    ParamPtrs pp;
    pp.p[0] = conv_w; pp.p[1] = conv_b; pp.p[2] = A_log; pp.p[3] = D_param;
    pp.p[4] = dt_w;   pp.p[5] = dt_b;   pp.p[6] = ln_g;  pp.p[7] = ln_b;
    canon_all<<<8656, 256, 0, stream>>>(pp, cpar, x, in_proj_w, out_w, cx,
                                        x_proj_w, wpad, dp);

    // 1. in_proj: xz = x @ in_proj_w^T   (M=2048, N=4096, K=1024), bf16 out
    gemm8<0><<<dim3(16, 16, 1), 512, 147456, stream>>>(cx, cw1, xz,
                                                       2048, 4096, 1024, 1024, 1024);
    // 2. causal conv4 + silu -> bf16
    conv_silu<<<2048, 256, 0, stream>>>(xz, cpar, xb16);
    // 3. x_proj GEMM, split-K 8x: xpart[z] = xb16 @ wpad^T (K seg 256), then reduce
    gemm_bt<1><<<dim3(16, 1, 8), 256, 0, stream>>>(xb16, wpad, xpart, 2048, 128, 256, 2048, 2048);
    reduce_parts<<<256, 256, 0, stream>>>(xpart, proj, 65536, 8);
    // 4. chunked parallel scan (CCH=32 chunks of CT=32)
    scan_p1<<<dim3(8, CCH, 2), 256, 0, stream>>>(xb16, proj, cpar, PS);
    scan_comb<<<256, 256, 0, stream>>>(PS, H);
    scan_p2<<<dim3(8, CCH, 2), 256, 0, stream>>>(xb16, proj, cpar, H, y);
    // 5. layernorm + silu(z) gate (yn overlays xb16)
    ln_silu<<<2048, 256, 0, stream>>>(y, xz, cpar, yn);
    // 6. out proj, split-K 4x: gpart[z] = yn @ out_w^T (K seg 512), then reduce
    gemm8<1><<<dim3(16, 4, 4), 512, 147456, stream>>>(yn, cwo, gpart,
                                                      2048, 1024, 512, 2048, 2048);
    reduce_parts<<<2048, 256, 0, stream>>>(gpart, (float*)d_out, 524288, 4);
}

// Round 3
// 234.267 us; speedup vs baseline: 1.0939x; 1.0308x over previous
//
#include <hip/hip_runtime.h>

typedef unsigned short u16;
typedef unsigned int u32;
typedef __bf16 bf16x8 __attribute__((ext_vector_type(8)));
typedef float f32x4 __attribute__((ext_vector_type(4)));
typedef unsigned short ushort8 __attribute__((ext_vector_type(8)));

__device__ __forceinline__ float bf2f(u16 b) {
    return __uint_as_float(((u32)b) << 16);
}
__device__ __forceinline__ u16 f2bf(float f) {
    u32 u = __float_as_uint(f);
    return (u16)((u + 0x7fffu + ((u >> 16) & 1u)) >> 16);
}

// fp32 canonical param block (element offsets)
#define P_CONVW 0       // 2048*4
#define P_CONVB 8192    // 2048
#define P_ALOG  10240   // 2048*16
#define P_DPAR  43008   // 2048
#define P_DTW   45056   // 2048
#define P_DTB   47104   // 2048
#define P_LNG   49152   // 2048
#define P_LNB   51200   // 2048
#define P_TOTAL 53248

// scan chunking
#define CCH 32            // chunks over L=1024
#define CT  32            // timesteps per chunk
#define CHUNKTOT 2097152  // B*CCH*16*2048
#define PSTRIDE 128       // proj row stride (N padded for MFMA)

// canon segment offsets (uint2 units)
#define CV_X   524288
#define CV_W1  1572864
#define CV_TOT 2097152

struct ParamPtrs { const void* p[8]; };

// ---------------------------------------------------------------------------
// Merged canonicalization kernel.
// ---------------------------------------------------------------------------
__global__ __launch_bounds__(256) void canon_all(ParamPtrs pp, float* __restrict__ cpar,
                                                 const void* __restrict__ sx,
                                                 const void* __restrict__ sw1,
                                                 const void* __restrict__ swo,
                                                 u16* __restrict__ cx,
                                                 const void* __restrict__ sxp,
                                                 u16* __restrict__ wpad,
                                                 const u16* __restrict__ dp) {
    const bool isbf = (dp[0] != 0);
    const int blk = blockIdx.x;
    const int tid = threadIdx.x;
    if (blk < 8192) {
        const int i = blk * 256 + tid;
        const void* src;
        int off;
        if (i < CV_X)       { src = sx;  off = i; }
        else if (i < CV_W1) { src = sw1; off = i - CV_X; }
        else                { src = swo; off = i - CV_W1; }
        if (isbf) {
            ((uint2*)cx)[i] = ((const uint2*)src)[off];
        } else {
            const float4 v = ((const float4*)src)[off];
            uint2 o;
            o.x = (u32)f2bf(v.x) | ((u32)f2bf(v.y) << 16);
            o.y = (u32)f2bf(v.z) | ((u32)f2bf(v.w) << 16);
            ((uint2*)cx)[i] = o;
        }
    } else if (blk < 8400) {
        const int i = (blk - 8192) * 256 + tid;
        int seg, off;
        if (i < P_CONVB)      { seg = 0; off = i; }
        else if (i < P_ALOG)  { seg = 1; off = i - P_CONVB; }
        else if (i < P_DPAR)  { seg = 2; off = i - P_ALOG; }
        else if (i < P_DTW)   { seg = 3; off = i - P_DPAR; }
        else if (i < P_DTB)   { seg = 4; off = i - P_DTW; }
        else if (i < P_LNG)   { seg = 5; off = i - P_DTB; }
        else if (i < P_LNB)   { seg = 6; off = i - P_LNG; }
        else                  { seg = 7; off = i - P_LNB; }
        cpar[i] = isbf ? bf2f(((const u16*)pp.p[seg])[off]) : ((const float*)pp.p[seg])[off];
    } else {
        const int i = (blk - 8400) * 256 + tid;  // over 65536
        const int idx = i * 4;
        const int row = idx >> 11;
        u16 o[4];
#pragma unroll
        for (int q = 0; q < 4; ++q) {
            float v = 0.f;
            if (row < 33)
                v = isbf ? bf2f(((const u16*)sxp)[idx + q]) : ((const float*)sxp)[idx + q];
            o[q] = f2bf(v);
        }
        *(uint2*)&wpad[idx] = *(uint2*)o;
    }
}

// ---------------------------------------------------------------------------
// gemm8: BM=128, BN=256, BK=64, 512 threads (8 waves, 2Mx4N).
// Triple-buffered LDS (144 KiB), counted vmcnt(6), raw s_barrier, XOR-swizzled
// LDS via pre-swizzled global source, setprio around MFMA clusters.
// MODE 0: bf16 store; MODE 1: f32 store at + z*M*N.
// ---------------------------------------------------------------------------
__device__ __forceinline__ bf16x8 lds_frag(const char* smem, u32 base, int row, int kk,
                                           int quad, u32 xorv) {
    const u32 addr = (base + (u32)(row * 128 + kk * 64 + quad * 16)) ^ xorv;
    return *(const bf16x8*)(smem + addr);
}

template <int MODE>
__global__ __launch_bounds__(512, 2) void gemm8(const u16* __restrict__ A,
                                                const u16* __restrict__ Bw,
                                                void* __restrict__ C,
                                                int M, int N, int Kseg,
                                                int lda, int ldb) {
    extern __shared__ char smem[];
    const int bm = blockIdx.x, bn = blockIdx.y;
    const int kbase = blockIdx.z * Kseg;
    const int tid = threadIdx.x;
    const int lane = tid & 63, wave = tid >> 6;
    const int wm = wave >> 2, wn = wave & 3;
    const int l16 = lane & 15, quad = lane >> 4;
    const int NT = Kseg >> 6;
    const u32 xorv = (u32)((l16 & 7) << 4);

    const int rIss = wave * 8 + (lane >> 3);
    const int logC = (lane & 7) ^ ((lane >> 3) & 7);
    size_t aSrc[2], bSrc[4];
#pragma unroll
    for (int j = 0; j < 2; ++j)
        aSrc[j] = (size_t)(bm * 128 + j * 64 + rIss) * lda + logC * 8 + kbase;
#pragma unroll
    for (int j = 0; j < 4; ++j)
        bSrc[j] = (size_t)(bn * 256 + j * 64 + rIss) * ldb + logC * 8 + kbase;
    const u32 ldsW = (u32)(wave * 1024);

#define SG_A(slot, j, kel) __builtin_amdgcn_global_load_lds( \
        (const u32*)(A + aSrc[j] + (kel)), (u32*)(smem + (slot) + (j) * 8192 + ldsW), 16, 0, 0)
#define SG_B(slot, j, kel) __builtin_amdgcn_global_load_lds( \
        (const u32*)(Bw + bSrc[j] + (kel)), (u32*)(smem + (slot) + (j) * 8192 + ldsW), 16, 0, 0)

    const u32 sA0 = 0, sA1 = 16384, sA2 = 32768;
    const u32 sB0 = 49152, sB1 = 81920, sB2 = 114688;

    SG_A(sA0, 0, 0); SG_A(sA0, 1, 0);
    SG_B(sB0, 0, 0); SG_B(sB0, 1, 0); SG_B(sB0, 2, 0); SG_B(sB0, 3, 0);
    SG_A(sA1, 0, 64); SG_A(sA1, 1, 64);
    SG_B(sB1, 0, 64); SG_B(sB1, 1, 64); SG_B(sB1, 2, 64); SG_B(sB1, 3, 64);
    asm volatile("s_waitcnt vmcnt(6)" ::: "memory");
    __builtin_amdgcn_s_barrier();
    __builtin_amdgcn_sched_barrier(0);

    u32 curA = sA0, nxtA = sA1, stgA = sA2;
    u32 curB = sB0, nxtB = sB1, stgB = sB2;
    int kStage = 128;

    f32x4 acc[4][4] = {};
    bf16x8 a[4][2], b[4][2];

    for (int t = 0; t < NT; ++t) {
        const bool doStage = (t + 2) < NT;
#pragma unroll
        for (int mt = 0; mt < 4; ++mt)
#pragma unroll
            for (int kk = 0; kk < 2; ++kk)
                a[mt][kk] = lds_frag(smem, curA, wm * 64 + mt * 16 + l16, kk, quad, xorv);
#pragma unroll
        for (int nt = 0; nt < 2; ++nt)
#pragma unroll
            for (int kk = 0; kk < 2; ++kk)
                b[nt][kk] = lds_frag(smem, curB, wn * 64 + nt * 16 + l16, kk, quad, xorv);
        if (doStage) { SG_A(stgA, 0, kStage); SG_A(stgA, 1, kStage); SG_B(stgB, 0, kStage); }
        __builtin_amdgcn_s_setprio(1);
#pragma unroll
        for (int mt = 0; mt < 4; ++mt)
#pragma unroll
            for (int nt = 0; nt < 2; ++nt)
#pragma unroll
                for (int kk = 0; kk < 2; ++kk)
                    acc[mt][nt] = __builtin_amdgcn_mfma_f32_16x16x32_bf16(
                        a[mt][kk], b[nt][kk], acc[mt][nt], 0, 0, 0);
        __builtin_amdgcn_s_setprio(0);
#pragma unroll
        for (int nt = 2; nt < 4; ++nt)
#pragma unroll
            for (int kk = 0; kk < 2; ++kk)
                b[nt][kk] = lds_frag(smem, curB, wn * 64 + nt * 16 + l16, kk, quad, xorv);
        if (doStage) { SG_B(stgB, 1, kStage); SG_B(stgB, 2, kStage); SG_B(stgB, 3, kStage); }
        __builtin_amdgcn_s_setprio(1);
#pragma unroll
        for (int mt = 0; mt < 4; ++mt)
#pragma unroll
            for (int nt = 2; nt < 4; ++nt)
#pragma unroll
                for (int kk = 0; kk < 2; ++kk)
                    acc[mt][nt] = __builtin_amdgcn_mfma_f32_16x16x32_bf16(
                        a[mt][kk], b[nt][kk], acc[mt][nt], 0, 0, 0);
        __builtin_amdgcn_s_setprio(0);
        if (t < NT - 1) {
            if (doStage) asm volatile("s_waitcnt vmcnt(6)" ::: "memory");
            else         asm volatile("s_waitcnt vmcnt(0)" ::: "memory");
            __builtin_amdgcn_s_barrier();
            __builtin_amdgcn_sched_barrier(0);
            u32 tA = curA; curA = nxtA; nxtA = stgA; stgA = tA;
            u32 tB = curB; curB = nxtB; nxtB = stgB; stgB = tB;
            kStage += 64;
        }
    }
#undef SG_A
#undef SG_B

    float* Cf = (float*)C + (MODE == 1 ? (size_t)blockIdx.z * M * N : (size_t)0);
#pragma unroll
    for (int mt = 0; mt < 4; ++mt) {
#pragma unroll
        for (int r = 0; r < 4; ++r) {
            const int row = bm * 128 + wm * 64 + mt * 16 + quad * 4 + r;
#pragma unroll
            for (int nt = 0; nt < 4; ++nt) {
                const int col = bn * 256 + wn * 64 + nt * 16 + l16;
                if (MODE == 0)
                    ((u16*)C)[(size_t)row * N + col] = f2bf(acc[mt][nt][r]);
                else
                    Cf[(size_t)row * N + col] = acc[mt][nt][r];
            }
        }
    }
}

// ---------------------------------------------------------------------------
// OLD GEMM (m97 structure) for the skinny x_proj (N=128).
// ---------------------------------------------------------------------------
template <int MODE>
__global__ __launch_bounds__(256) void gemm_bt(const u16* __restrict__ A,
                                               const u16* __restrict__ Bw,
                                               void* __restrict__ C,
                                               int M, int N, int Kseg,
                                               int lda, int ldb) {
    const int bm = blockIdx.x;
    const int bn = blockIdx.y;
    const int kbase = blockIdx.z * Kseg;
    const int tid = threadIdx.x;
    const int lane = tid & 63;
    const int wave = tid >> 6;
    const int wm = wave >> 1, wn = wave & 1;
    const int l16 = lane & 15, quad = lane >> 4;

    __shared__ __align__(16) u16 sA[128 * 32];
    __shared__ __align__(16) u16 sB[128 * 32];

    f32x4 acc[4][4] = {};

    const int rsub = lane >> 2;
    const int csub = (lane & 3) * 8;

    for (int k0 = 0; k0 < Kseg; k0 += 32) {
        const int kc = kbase + k0 + csub;
        __syncthreads();
#pragma unroll
        for (int q = 0; q < 2; ++q) {
            const int g = wave + 4 * q;
            const int row = g * 16 + rsub;
            __builtin_amdgcn_global_load_lds(
                (const u32*)&A[(size_t)(bm * 128 + row) * lda + kc],
                (u32*)&sA[g * 512], 16, 0, 0);
            __builtin_amdgcn_global_load_lds(
                (const u32*)&Bw[(size_t)(bn * 128 + row) * ldb + kc],
                (u32*)&sB[g * 512], 16, 0, 0);
        }
        __syncthreads();

        bf16x8 af[4], bg[4];
#pragma unroll
        for (int t = 0; t < 4; ++t) {
            af[t] = *(const bf16x8*)&sA[(wm * 64 + t * 16 + l16) * 32 + quad * 8];
            bg[t] = *(const bf16x8*)&sB[(wn * 64 + t * 16 + l16) * 32 + quad * 8];
        }
#pragma unroll
        for (int mt = 0; mt < 4; ++mt)
#pragma unroll
            for (int nt = 0; nt < 4; ++nt)
                acc[mt][nt] = __builtin_amdgcn_mfma_f32_16x16x32_bf16(
                    af[mt], bg[nt], acc[mt][nt], 0, 0, 0);
    }

    float* Cf = (float*)C + (MODE == 1 ? (size_t)blockIdx.z * M * N : (size_t)0);
#pragma unroll
    for (int mt = 0; mt < 4; ++mt) {
#pragma unroll
        for (int r = 0; r < 4; ++r) {
            const int row = bm * 128 + wm * 64 + mt * 16 + quad * 4 + r;
#pragma unroll
            for (int nt = 0; nt < 4; ++nt) {
                const int col = bn * 128 + wn * 64 + nt * 16 + l16;
                if (MODE == 0)
                    ((u16*)C)[(size_t)row * N + col] = f2bf(acc[mt][nt][r]);
                else
                    Cf[(size_t)row * N + col] = acc[mt][nt][r];
            }
        }
    }
}

// sum P parts of length n (floats), float4-vectorized
__global__ __launch_bounds__(256) void reduce_parts(const float* __restrict__ src,
                                                    float* __restrict__ dst,
                                                    int n4, int parts) {
    const int i = blockIdx.x * 256 + threadIdx.x;
    if (i >= n4) return;
    float4 s = ((const float4*)src)[i];
    for (int p = 1; p < parts; ++p) {
        const float4 v = ((const float4*)src)[(size_t)p * n4 + i];
        s.x += v.x; s.y += v.y; s.z += v.z; s.w += v.w;
    }
    ((float4*)dst)[i] = s;
}

// ---------------------------------------------------------------------------
// Depthwise causal conv (D_CONV=4) + SiLU, vectorized 8-wide over d.
// ---------------------------------------------------------------------------
__global__ __launch_bounds__(256) void conv_silu(const u16* __restrict__ xz,
                                                 const float* __restrict__ par,
                                                 u16* __restrict__ xb16) {
    const int idx = blockIdx.x * 256 + threadIdx.x;  // over 2*1024*256
    const int d8 = idx & 255;
    const int bl = idx >> 8;
    const int l = bl & 1023;
    const int d0 = d8 * 8;

    float acc[8];
    {
        const float4 b0 = *(const float4*)&par[P_CONVB + d0];
        const float4 b1 = *(const float4*)&par[P_CONVB + d0 + 4];
        acc[0] = b0.x; acc[1] = b0.y; acc[2] = b0.z; acc[3] = b0.w;
        acc[4] = b1.x; acc[5] = b1.y; acc[6] = b1.z; acc[7] = b1.w;
    }
    float warr[8][4];
#pragma unroll
    for (int q = 0; q < 8; ++q) {
        const float4 w = *(const float4*)&par[P_CONVW + (d0 + q) * 4];
        warr[q][0] = w.x; warr[q][1] = w.y; warr[q][2] = w.z; warr[q][3] = w.w;
    }
#pragma unroll
    for (int k = 0; k < 4; ++k) {
        const int ls = l + k - 3;
        if (ls >= 0) {
            const ushort8 xv = *(const ushort8*)&xz[(size_t)(bl + k - 3) * 4096 + d0];
#pragma unroll
            for (int q = 0; q < 8; ++q)
                acc[q] = fmaf(bf2f(xv[q]), warr[q][k], acc[q]);
        }
    }
    u16 o[8];
#pragma unroll
    for (int q = 0; q < 8; ++q) {
        const float s = acc[q] / (1.f + __expf(-acc[q]));
        o[q] = f2bf(s);
    }
    *(uint4*)&xb16[(size_t)bl * 2048 + d0] = *(uint4*)o;
}

// ---------------------------------------------------------------------------
// Chunked parallel scan, pass 1.  n-split: thread pair (2k,2k+1) shares d,
// covers n-halves [0,8) / [8,16).  grid (16, CCH, 2), 1024 blocks.
// ---------------------------------------------------------------------------
__global__ __launch_bounds__(256) void scan_p1(const u16* __restrict__ xb16,
                                               const float* __restrict__ proj,
                                               const float* __restrict__ par,
                                               float* __restrict__ PS) {
    const int tid = threadIdx.x;
    const int half = tid & 1;
    const int d = blockIdx.x * 128 + (tid >> 1);
    const int c = blockIdx.y;
    const int b = blockIdx.z;
    const int nb = half * 8;
    __shared__ float sp[CT][33];
    const size_t row0 = (size_t)b * 1024 + c * CT;
    for (int f = tid; f < CT * 33; f += 256) {
        const int i = f / 33, j = f - i * 33;
        sp[i][j] = proj[(row0 + i) * PSTRIDE + j];
    }
    float Aneg[8];
#pragma unroll
    for (int n = 0; n < 8; ++n) Aneg[n] = -__expf(par[P_ALOG + d * 16 + nb + n]);
    const float dtw = par[P_DTW + d], dtb = par[P_DTB + d];
    __syncthreads();

    float h[8] = {}, P[8];
#pragma unroll
    for (int n = 0; n < 8; ++n) P[n] = 1.f;

    float xv = bf2f(xb16[row0 * 2048 + d]);
    for (int i = 0; i < CT; ++i) {
        const float xv_next = (i + 1 < CT) ? bf2f(xb16[(row0 + i + 1) * 2048 + d]) : 0.f;
        const float darg = fmaf(sp[i][0], dtw, dtb);
        const float dt = (darg > 20.f) ? darg : __logf(1.f + __expf(darg));
        const float xdt = xv * dt;
#pragma unroll
        for (int n = 0; n < 8; ++n) {
            const float dA = __expf(dt * Aneg[n]);
            P[n] *= dA;
            h[n] = fmaf(dA, h[n], xdt * sp[i][1 + nb + n]);
        }
        xv = xv_next;
    }
    const size_t base = (((size_t)b * CCH + c) * 16) * 2048 + d;
#pragma unroll
    for (int n = 0; n < 8; ++n) {
        PS[base + (size_t)(nb + n) * 2048] = P[n];
        PS[CHUNKTOT + base + (size_t)(nb + n) * 2048] = h[n];
    }
}

// ---------------------------------------------------------------------------
// Combine: per (b,d,n), serial scan over CCH chunks.
// ---------------------------------------------------------------------------
__global__ __launch_bounds__(256) void scan_comb(const float* __restrict__ PS,
                                                 float* __restrict__ H) {
    const int t = blockIdx.x * 256 + threadIdx.x;  // 65536 total
    const int d = t & 2047;
    const int n = (t >> 11) & 15;
    const int b = t >> 15;
    float h = 0.f;
#pragma unroll
    for (int c = 0; c < CCH; ++c) {
        const size_t idx = (((size_t)b * CCH + c) * 16 + n) * 2048 + d;
        H[idx] = h;
        h = fmaf(PS[idx], h, PS[CHUNKTOT + idx]);
    }
}

// ---------------------------------------------------------------------------
// Pass 2: replay from true initial state H_c, emit y (bf16).  n-split as p1;
// cross-pair reduce via __shfl_xor(acc,1); even lane writes y.
// ---------------------------------------------------------------------------
__global__ __launch_bounds__(256) void scan_p2(const u16* __restrict__ xb16,
                                               const float* __restrict__ proj,
                                               const float* __restrict__ par,
                                               const float* __restrict__ H,
                                               u16* __restrict__ y) {
    const int tid = threadIdx.x;
    const int half = tid & 1;
    const int d = blockIdx.x * 128 + (tid >> 1);
    const int c = blockIdx.y;
    const int b = blockIdx.z;
    const int nb = half * 8;
    __shared__ float sp[CT][33];
    const size_t row0 = (size_t)b * 1024 + c * CT;
    for (int f = tid; f < CT * 33; f += 256) {
        const int i = f / 33, j = f - i * 33;
        sp[i][j] = proj[(row0 + i) * PSTRIDE + j];
    }
    float Aneg[8], h[8];
    const size_t hbase = (((size_t)b * CCH + c) * 16) * 2048 + d;
#pragma unroll
    for (int n = 0; n < 8; ++n) {
        Aneg[n] = -__expf(par[P_ALOG + d * 16 + nb + n]);
        h[n] = H[hbase + (size_t)(nb + n) * 2048];
    }
    const float dtw = par[P_DTW + d], dtb = par[P_DTB + d];
    const float Dp = par[P_DPAR + d];
    __syncthreads();

    float xv = bf2f(xb16[row0 * 2048 + d]);
    for (int i = 0; i < CT; ++i) {
        const float xv_next = (i + 1 < CT) ? bf2f(xb16[(row0 + i + 1) * 2048 + d]) : 0.f;
        const float darg = fmaf(sp[i][0], dtw, dtb);
        const float dt = (darg > 20.f) ? darg : __logf(1.f + __expf(darg));
        const float xdt = xv * dt;
        float acc = 0.f;
#pragma unroll
        for (int n = 0; n < 8; ++n) {
            const float dA = __expf(dt * Aneg[n]);
            h[n] = fmaf(dA, h[n], xdt * sp[i][1 + nb + n]);
            acc = fmaf(h[n], sp[i][17 + nb + n], acc);
        }
        acc += __shfl_xor(acc, 1);
        if (!half)
            y[(row0 + i) * 2048 + d] = f2bf(fmaf(xv, Dp, acc));
        xv = xv_next;
    }
}

// ---------------------------------------------------------------------------
// LayerNorm over D_INNER + *silu(z); vectorized 8-wide contiguous per thread.
// ---------------------------------------------------------------------------
__global__ __launch_bounds__(256) void ln_silu(const u16* __restrict__ y,
                                               const u16* __restrict__ xz,
                                               const float* __restrict__ par,
                                               u16* __restrict__ yn) {
    const int row = blockIdx.x;
    const int tid = threadIdx.x;
    const int lane = tid & 63, wave = tid >> 6;
    const int d0 = tid * 8;
    const ushort8 vy = *(const ushort8*)&y[(size_t)row * 2048 + d0];
    float v[8];
    float s = 0.f, s2 = 0.f;
#pragma unroll
    for (int i = 0; i < 8; ++i) {
        v[i] = bf2f(vy[i]);
        s += v[i];
        s2 = fmaf(v[i], v[i], s2);
    }
    s += __shfl_xor(s, 1); s2 += __shfl_xor(s2, 1);
    s += __shfl_xor(s, 2); s2 += __shfl_xor(s2, 2);
    s += __shfl_xor(s, 4); s2 += __shfl_xor(s2, 4);
    s += __shfl_xor(s, 8); s2 += __shfl_xor(s2, 8);
    s += __shfl_xor(s, 16); s2 += __shfl_xor(s2, 16);
    s += __shfl_xor(s, 32); s2 += __shfl_xor(s2, 32);
    __shared__ float rs[4], rs2[4];
    if (lane == 0) { rs[wave] = s; rs2[wave] = s2; }
    __syncthreads();
    const float ts = rs[0] + rs[1] + rs[2] + rs[3];
    const float ts2 = rs2[0] + rs2[1] + rs2[2] + rs2[3];
    const float mu = ts * (1.f / 2048.f);
    const float var = ts2 * (1.f / 2048.f) - mu * mu;
    const float rstd = rsqrtf(var + 1e-5f);

    const ushort8 vz = *(const ushort8*)&xz[(size_t)row * 4096 + 2048 + d0];
    float g[8], bb[8];
    {
        const float4 g0 = *(const float4*)&par[P_LNG + d0];
        const float4 g1 = *(const float4*)&par[P_LNG + d0 + 4];
        g[0] = g0.x; g[1] = g0.y; g[2] = g0.z; g[3] = g0.w;
        g[4] = g1.x; g[5] = g1.y; g[6] = g1.z; g[7] = g1.w;
        const float4 b0 = *(const float4*)&par[P_LNB + d0];
        const float4 b1 = *(const float4*)&par[P_LNB + d0 + 4];
        bb[0] = b0.x; bb[1] = b0.y; bb[2] = b0.z; bb[3] = b0.w;
        bb[4] = b1.x; bb[5] = b1.y; bb[6] = b1.z; bb[7] = b1.w;
    }
    u16 o[8];
#pragma unroll
    for (int i = 0; i < 8; ++i) {
        float t = (v[i] - mu) * rstd * g[i] + bb[i];
        const float z = bf2f(vz[i]);
        t *= z / (1.f + __expf(-z));
        o[i] = f2bf(t);
    }
    *(uint4*)&yn[(size_t)row * 2048 + d0] = *(uint4*)o;
}

// ---------------------------------------------------------------------------
extern "C" void kernel_launch(void* const* d_in, const int* in_sizes, int n_in,
                              void* d_out, int out_size, void* d_ws, size_t ws_size,
                              hipStream_t stream) {
    const void* x         = d_in[0];   // (2,1024,1024) fp32
    const void* in_proj_w = d_in[1];
    const void* conv_w    = d_in[2];
    const void* conv_b    = d_in[3];
    const void* x_proj_w  = d_in[4];
    const void* A_log     = d_in[5];
    const void* D_param   = d_in[6];
    const void* dt_w      = d_in[7];
    const void* dt_b      = d_in[8];
    const void* out_w     = d_in[9];
    const void* ln_g      = d_in[10];
    const void* ln_b      = d_in[11];
    const u16* dp = (const u16*)D_param;

    // workspace layout
    float* cpar = (float*)d_ws;              // 53,248 f32
    u16* cx     = (u16*)(cpar + P_TOTAL);    // 2,097,152 u16 (4 MB)
    u16* cw1    = cx + 2097152;              // 4,194,304 u16 (8 MB)
    u16* cwo    = cw1 + 4194304;             // 2,097,152 u16 (4 MB)
    u16* xz     = cwo + 2097152;             // 8,388,608 u16 (16 MB)
    u16* xb16   = xz + 8388608;              // 4,194,304 u16 (8 MB)
    u16* y      = xb16 + 4194304;            // 4,194,304 u16 (8 MB)
    u16* wpad   = y + 4194304;               // 262,144 u16   (0.5 MB)
    float* proj = (float*)(wpad + 262144);   // 2048*128 f32  (1 MB)
    float* PS   = proj + 262144;             // 2*CHUNKTOT f32 (16 MB)
    float* H    = PS + 2 * CHUNKTOT;         // CHUNKTOT f32   (8 MB)
    float* gpart = H + CHUNKTOT;             // 4*2048*1024 f32 (32 MB)
    // overlays:
    float* xpart = gpart;                    // 16*2048*128 f32 (16 MB) — dead before gemm3
    u16* yn      = xb16;                     // xb16 dead after scan_p2

    // raise dynamic-LDS cap for the 144 KiB GEMM (host-side, graph-safe)
    static bool attrSet = false;
    if (!attrSet) {
        hipFuncSetAttribute(reinterpret_cast<const void*>(&gemm8<0>),
                            hipFuncAttributeMaxDynamicSharedMemorySize, 147456);
        hipFuncSetAttribute(reinterpret_cast<const void*>(&gemm8<1>),
                            hipFuncAttributeMaxDynamicSharedMemorySize, 147456);
        attrSet = true;
    }

    // 0. canonicalize params + convert GEMM operands to bf16
    ParamPtrs pp;
    pp.p[0] = conv_w; pp.p[1] = conv_b; pp.p[2] = A_log; pp.p[3] = D_param;
    pp.p[4] = dt_w;   pp.p[5] = dt_b;   pp.p[6] = ln_g;  pp.p[7] = ln_b;
    canon_all<<<8656, 256, 0, stream>>>(pp, cpar, x, in_proj_w, out_w, cx,
                                        x_proj_w, wpad, dp);

    // 1. in_proj: xz = x @ in_proj_w^T   (M=2048, N=4096, K=1024), bf16 out
    gemm8<0><<<dim3(16, 16, 1), 512, 147456, stream>>>(cx, cw1, xz,
                                                       2048, 4096, 1024, 1024, 1024);
    // 2. causal conv4 + silu -> bf16
    conv_silu<<<2048, 256, 0, stream>>>(xz, cpar, xb16);
    // 3. x_proj GEMM, split-K 16 (full grid): xpart[z] = xb16 @ wpad^T (K seg 128)
    gemm_bt<1><<<dim3(16, 1, 16), 256, 0, stream>>>(xb16, wpad, xpart, 2048, 128, 128, 2048, 2048);
    reduce_parts<<<256, 256, 0, stream>>>(xpart, proj, 65536, 16);
    // 4. chunked parallel scan (n-split: 1024 blocks in p1/p2)
    scan_p1<<<dim3(16, CCH, 2), 256, 0, stream>>>(xb16, proj, cpar, PS);
    scan_comb<<<256, 256, 0, stream>>>(PS, H);
    scan_p2<<<dim3(16, CCH, 2), 256, 0, stream>>>(xb16, proj, cpar, H, y);
    // 5. layernorm + silu(z) gate (yn overlays xb16)
    ln_silu<<<2048, 256, 0, stream>>>(y, xz, cpar, yn);
    // 6. out proj, split-K 4x: gpart[z] = yn @ out_w^T (K seg 512), then reduce
    gemm8<1><<<dim3(16, 4, 4), 512, 147456, stream>>>(yn, cwo, gpart,
                                                      2048, 1024, 512, 2048, 2048);
    reduce_parts<<<2048, 256, 0, stream>>>(gpart, (float*)d_out, 524288, 4);
}

// Round 4
// 233.274 us; speedup vs baseline: 1.0986x; 1.0043x over previous
//
#include <hip/hip_runtime.h>

typedef unsigned short u16;
typedef unsigned int u32;
typedef __bf16 bf16x8 __attribute__((ext_vector_type(8)));
typedef float f32x4 __attribute__((ext_vector_type(4)));
typedef unsigned short ushort8 __attribute__((ext_vector_type(8)));

__device__ __forceinline__ float bf2f(u16 b) {
    return __uint_as_float(((u32)b) << 16);
}
__device__ __forceinline__ u16 f2bf(float f) {
    u32 u = __float_as_uint(f);
    return (u16)((u + 0x7fffu + ((u >> 16) & 1u)) >> 16);
}

// fp32 canonical param block (element offsets)
#define P_CONVW 0       // 2048*4
#define P_CONVB 8192    // 2048
#define P_ALOG  10240   // 2048*16
#define P_DPAR  43008   // 2048
#define P_DTW   45056   // 2048
#define P_DTB   47104   // 2048
#define P_LNG   49152   // 2048
#define P_LNB   51200   // 2048
#define P_TOTAL 53248

// scan chunking
#define CCH 32            // chunks over L=1024
#define CT  32            // timesteps per chunk
#define CHUNKTOT 2097152  // B*CCH*16*2048
#define PSTRIDE 128       // proj row stride (N padded for MFMA)

// canon segment offsets (uint2 units)
#define CV_X   524288
#define CV_W1  1572864
#define CV_TOT 2097152

struct ParamPtrs { const void* p[8]; };

// ---------------------------------------------------------------------------
// Merged canonicalization kernel.
// ---------------------------------------------------------------------------
__global__ __launch_bounds__(256) void canon_all(ParamPtrs pp, float* __restrict__ cpar,
                                                 const void* __restrict__ sx,
                                                 const void* __restrict__ sw1,
                                                 const void* __restrict__ swo,
                                                 u16* __restrict__ cx,
                                                 const void* __restrict__ sxp,
                                                 u16* __restrict__ wpad,
                                                 const u16* __restrict__ dp) {
    const bool isbf = (dp[0] != 0);
    const int blk = blockIdx.x;
    const int tid = threadIdx.x;
    if (blk < 8192) {
        const int i = blk * 256 + tid;
        const void* src;
        int off;
        if (i < CV_X)       { src = sx;  off = i; }
        else if (i < CV_W1) { src = sw1; off = i - CV_X; }
        else                { src = swo; off = i - CV_W1; }
        if (isbf) {
            ((uint2*)cx)[i] = ((const uint2*)src)[off];
        } else {
            const float4 v = ((const float4*)src)[off];
            uint2 o;
            o.x = (u32)f2bf(v.x) | ((u32)f2bf(v.y) << 16);
            o.y = (u32)f2bf(v.z) | ((u32)f2bf(v.w) << 16);
            ((uint2*)cx)[i] = o;
        }
    } else if (blk < 8400) {
        const int i = (blk - 8192) * 256 + tid;
        int seg, off;
        if (i < P_CONVB)      { seg = 0; off = i; }
        else if (i < P_ALOG)  { seg = 1; off = i - P_CONVB; }
        else if (i < P_DPAR)  { seg = 2; off = i - P_ALOG; }
        else if (i < P_DTW)   { seg = 3; off = i - P_DPAR; }
        else if (i < P_DTB)   { seg = 4; off = i - P_DTW; }
        else if (i < P_LNG)   { seg = 5; off = i - P_DTB; }
        else if (i < P_LNB)   { seg = 6; off = i - P_LNG; }
        else                  { seg = 7; off = i - P_LNB; }
        cpar[i] = isbf ? bf2f(((const u16*)pp.p[seg])[off]) : ((const float*)pp.p[seg])[off];
    } else {
        const int i = (blk - 8400) * 256 + tid;  // over 65536
        const int idx = i * 4;
        const int row = idx >> 11;
        u16 o[4];
#pragma unroll
        for (int q = 0; q < 4; ++q) {
            float v = 0.f;
            if (row < 33)
                v = isbf ? bf2f(((const u16*)sxp)[idx + q]) : ((const float*)sxp)[idx + q];
            o[q] = f2bf(v);
        }
        *(uint2*)&wpad[idx] = *(uint2*)o;
    }
}

// ---------------------------------------------------------------------------
// gemm8: BM=128, BN=256, BK=64, 512 threads (8 waves, 2Mx4N).
// Triple-buffered LDS (144 KiB), counted vmcnt(6), raw s_barrier, XOR-swizzled
// LDS via pre-swizzled global source, setprio around MFMA clusters.
// MODE 0: bf16 store; MODE 1: f32 store at + z*M*N.
// ---------------------------------------------------------------------------
__device__ __forceinline__ bf16x8 lds_frag(const char* smem, u32 base, int row, int kk,
                                           int quad, u32 xorv) {
    const u32 addr = (base + (u32)(row * 128 + kk * 64 + quad * 16)) ^ xorv;
    return *(const bf16x8*)(smem + addr);
}

template <int MODE>
__global__ __launch_bounds__(512, 2) void gemm8(const u16* __restrict__ A,
                                                const u16* __restrict__ Bw,
                                                void* __restrict__ C,
                                                int M, int N, int Kseg,
                                                int lda, int ldb) {
    extern __shared__ char smem[];
    const int bm = blockIdx.x, bn = blockIdx.y;
    const int kbase = blockIdx.z * Kseg;
    const int tid = threadIdx.x;
    const int lane = tid & 63, wave = tid >> 6;
    const int wm = wave >> 2, wn = wave & 3;
    const int l16 = lane & 15, quad = lane >> 4;
    const int NT = Kseg >> 6;
    const u32 xorv = (u32)((l16 & 7) << 4);

    const int rIss = wave * 8 + (lane >> 3);
    const int logC = (lane & 7) ^ ((lane >> 3) & 7);
    size_t aSrc[2], bSrc[4];
#pragma unroll
    for (int j = 0; j < 2; ++j)
        aSrc[j] = (size_t)(bm * 128 + j * 64 + rIss) * lda + logC * 8 + kbase;
#pragma unroll
    for (int j = 0; j < 4; ++j)
        bSrc[j] = (size_t)(bn * 256 + j * 64 + rIss) * ldb + logC * 8 + kbase;
    const u32 ldsW = (u32)(wave * 1024);

#define SG_A(slot, j, kel) __builtin_amdgcn_global_load_lds( \
        (const u32*)(A + aSrc[j] + (kel)), (u32*)(smem + (slot) + (j) * 8192 + ldsW), 16, 0, 0)
#define SG_B(slot, j, kel) __builtin_amdgcn_global_load_lds( \
        (const u32*)(Bw + bSrc[j] + (kel)), (u32*)(smem + (slot) + (j) * 8192 + ldsW), 16, 0, 0)

    const u32 sA0 = 0, sA1 = 16384, sA2 = 32768;
    const u32 sB0 = 49152, sB1 = 81920, sB2 = 114688;

    SG_A(sA0, 0, 0); SG_A(sA0, 1, 0);
    SG_B(sB0, 0, 0); SG_B(sB0, 1, 0); SG_B(sB0, 2, 0); SG_B(sB0, 3, 0);
    SG_A(sA1, 0, 64); SG_A(sA1, 1, 64);
    SG_B(sB1, 0, 64); SG_B(sB1, 1, 64); SG_B(sB1, 2, 64); SG_B(sB1, 3, 64);
    asm volatile("s_waitcnt vmcnt(6)" ::: "memory");
    __builtin_amdgcn_s_barrier();
    __builtin_amdgcn_sched_barrier(0);

    u32 curA = sA0, nxtA = sA1, stgA = sA2;
    u32 curB = sB0, nxtB = sB1, stgB = sB2;
    int kStage = 128;

    f32x4 acc[4][4] = {};
    bf16x8 a[4][2], b[4][2];

    for (int t = 0; t < NT; ++t) {
        const bool doStage = (t + 2) < NT;
#pragma unroll
        for (int mt = 0; mt < 4; ++mt)
#pragma unroll
            for (int kk = 0; kk < 2; ++kk)
                a[mt][kk] = lds_frag(smem, curA, wm * 64 + mt * 16 + l16, kk, quad, xorv);
#pragma unroll
        for (int nt = 0; nt < 2; ++nt)
#pragma unroll
            for (int kk = 0; kk < 2; ++kk)
                b[nt][kk] = lds_frag(smem, curB, wn * 64 + nt * 16 + l16, kk, quad, xorv);
        if (doStage) { SG_A(stgA, 0, kStage); SG_A(stgA, 1, kStage); SG_B(stgB, 0, kStage); }
        __builtin_amdgcn_s_setprio(1);
#pragma unroll
        for (int mt = 0; mt < 4; ++mt)
#pragma unroll
            for (int nt = 0; nt < 2; ++nt)
#pragma unroll
                for (int kk = 0; kk < 2; ++kk)
                    acc[mt][nt] = __builtin_amdgcn_mfma_f32_16x16x32_bf16(
                        a[mt][kk], b[nt][kk], acc[mt][nt], 0, 0, 0);
        __builtin_amdgcn_s_setprio(0);
#pragma unroll
        for (int nt = 2; nt < 4; ++nt)
#pragma unroll
            for (int kk = 0; kk < 2; ++kk)
                b[nt][kk] = lds_frag(smem, curB, wn * 64 + nt * 16 + l16, kk, quad, xorv);
        if (doStage) { SG_B(stgB, 1, kStage); SG_B(stgB, 2, kStage); SG_B(stgB, 3, kStage); }
        __builtin_amdgcn_s_setprio(1);
#pragma unroll
        for (int mt = 0; mt < 4; ++mt)
#pragma unroll
            for (int nt = 2; nt < 4; ++nt)
#pragma unroll
                for (int kk = 0; kk < 2; ++kk)
                    acc[mt][nt] = __builtin_amdgcn_mfma_f32_16x16x32_bf16(
                        a[mt][kk], b[nt][kk], acc[mt][nt], 0, 0, 0);
        __builtin_amdgcn_s_setprio(0);
        if (t < NT - 1) {
            if (doStage) asm volatile("s_waitcnt vmcnt(6)" ::: "memory");
            else         asm volatile("s_waitcnt vmcnt(0)" ::: "memory");
            __builtin_amdgcn_s_barrier();
            __builtin_amdgcn_sched_barrier(0);
            u32 tA = curA; curA = nxtA; nxtA = stgA; stgA = tA;
            u32 tB = curB; curB = nxtB; nxtB = stgB; stgB = tB;
            kStage += 64;
        }
    }
#undef SG_A
#undef SG_B

    float* Cf = (float*)C + (MODE == 1 ? (size_t)blockIdx.z * M * N : (size_t)0);
#pragma unroll
    for (int mt = 0; mt < 4; ++mt) {
#pragma unroll
        for (int r = 0; r < 4; ++r) {
            const int row = bm * 128 + wm * 64 + mt * 16 + quad * 4 + r;
#pragma unroll
            for (int nt = 0; nt < 4; ++nt) {
                const int col = bn * 256 + wn * 64 + nt * 16 + l16;
                if (MODE == 0)
                    ((u16*)C)[(size_t)row * N + col] = f2bf(acc[mt][nt][r]);
                else
                    Cf[(size_t)row * N + col] = acc[mt][nt][r];
            }
        }
    }
}

// ---------------------------------------------------------------------------
// OLD GEMM (m97 structure) for the skinny x_proj (N=128).
// ---------------------------------------------------------------------------
template <int MODE>
__global__ __launch_bounds__(256) void gemm_bt(const u16* __restrict__ A,
                                               const u16* __restrict__ Bw,
                                               void* __restrict__ C,
                                               int M, int N, int Kseg,
                                               int lda, int ldb) {
    const int bm = blockIdx.x;
    const int bn = blockIdx.y;
    const int kbase = blockIdx.z * Kseg;
    const int tid = threadIdx.x;
    const int lane = tid & 63;
    const int wave = tid >> 6;
    const int wm = wave >> 1, wn = wave & 1;
    const int l16 = lane & 15, quad = lane >> 4;

    __shared__ __align__(16) u16 sA[128 * 32];
    __shared__ __align__(16) u16 sB[128 * 32];

    f32x4 acc[4][4] = {};

    const int rsub = lane >> 2;
    const int csub = (lane & 3) * 8;

    for (int k0 = 0; k0 < Kseg; k0 += 32) {
        const int kc = kbase + k0 + csub;
        __syncthreads();
#pragma unroll
        for (int q = 0; q < 2; ++q) {
            const int g = wave + 4 * q;
            const int row = g * 16 + rsub;
            __builtin_amdgcn_global_load_lds(
                (const u32*)&A[(size_t)(bm * 128 + row) * lda + kc],
                (u32*)&sA[g * 512], 16, 0, 0);
            __builtin_amdgcn_global_load_lds(
                (const u32*)&Bw[(size_t)(bn * 128 + row) * ldb + kc],
                (u32*)&sB[g * 512], 16, 0, 0);
        }
        __syncthreads();

        bf16x8 af[4], bg[4];
#pragma unroll
        for (int t = 0; t < 4; ++t) {
            af[t] = *(const bf16x8*)&sA[(wm * 64 + t * 16 + l16) * 32 + quad * 8];
            bg[t] = *(const bf16x8*)&sB[(wn * 64 + t * 16 + l16) * 32 + quad * 8];
        }
#pragma unroll
        for (int mt = 0; mt < 4; ++mt)
#pragma unroll
            for (int nt = 0; nt < 4; ++nt)
                acc[mt][nt] = __builtin_amdgcn_mfma_f32_16x16x32_bf16(
                    af[mt], bg[nt], acc[mt][nt], 0, 0, 0);
    }

    float* Cf = (float*)C + (MODE == 1 ? (size_t)blockIdx.z * M * N : (size_t)0);
#pragma unroll
    for (int mt = 0; mt < 4; ++mt) {
#pragma unroll
        for (int r = 0; r < 4; ++r) {
            const int row = bm * 128 + wm * 64 + mt * 16 + quad * 4 + r;
#pragma unroll
            for (int nt = 0; nt < 4; ++nt) {
                const int col = bn * 128 + wn * 64 + nt * 16 + l16;
                if (MODE == 0)
                    ((u16*)C)[(size_t)row * N + col] = f2bf(acc[mt][nt][r]);
                else
                    Cf[(size_t)row * N + col] = acc[mt][nt][r];
            }
        }
    }
}

// sum P parts of length n (floats), float4-vectorized
__global__ __launch_bounds__(256) void reduce_parts(const float* __restrict__ src,
                                                    float* __restrict__ dst,
                                                    int n4, int parts) {
    const int i = blockIdx.x * 256 + threadIdx.x;
    if (i >= n4) return;
    float4 s = ((const float4*)src)[i];
    for (int p = 1; p < parts; ++p) {
        const float4 v = ((const float4*)src)[(size_t)p * n4 + i];
        s.x += v.x; s.y += v.y; s.z += v.z; s.w += v.w;
    }
    ((float4*)dst)[i] = s;
}

// ---------------------------------------------------------------------------
// Depthwise causal conv (D_CONV=4) + SiLU, vectorized 8-wide over d.
// ---------------------------------------------------------------------------
__global__ __launch_bounds__(256) void conv_silu(const u16* __restrict__ xz,
                                                 const float* __restrict__ par,
                                                 u16* __restrict__ xb16) {
    const int idx = blockIdx.x * 256 + threadIdx.x;  // over 2*1024*256
    const int d8 = idx & 255;
    const int bl = idx >> 8;
    const int l = bl & 1023;
    const int d0 = d8 * 8;

    float acc[8];
    {
        const float4 b0 = *(const float4*)&par[P_CONVB + d0];
        const float4 b1 = *(const float4*)&par[P_CONVB + d0 + 4];
        acc[0] = b0.x; acc[1] = b0.y; acc[2] = b0.z; acc[3] = b0.w;
        acc[4] = b1.x; acc[5] = b1.y; acc[6] = b1.z; acc[7] = b1.w;
    }
    float warr[8][4];
#pragma unroll
    for (int q = 0; q < 8; ++q) {
        const float4 w = *(const float4*)&par[P_CONVW + (d0 + q) * 4];
        warr[q][0] = w.x; warr[q][1] = w.y; warr[q][2] = w.z; warr[q][3] = w.w;
    }
#pragma unroll
    for (int k = 0; k < 4; ++k) {
        const int ls = l + k - 3;
        if (ls >= 0) {
            const ushort8 xv = *(const ushort8*)&xz[(size_t)(bl + k - 3) * 4096 + d0];
#pragma unroll
            for (int q = 0; q < 8; ++q)
                acc[q] = fmaf(bf2f(xv[q]), warr[q][k], acc[q]);
        }
    }
    u16 o[8];
#pragma unroll
    for (int q = 0; q < 8; ++q) {
        const float s = acc[q] / (1.f + __expf(-acc[q]));
        o[q] = f2bf(s);
    }
    *(uint4*)&xb16[(size_t)bl * 2048 + d0] = *(uint4*)o;
}

// ---------------------------------------------------------------------------
// Fused chunked scan: p1 + combine + p2 in one kernel.
// Block: 4 d-columns x all 32 chunks.  Threads 256: h=t&1 (n-half),
// dsub=(t>>1)&3, c=t>>3.  Chunk summaries (P,S) live in LDS; the serial
// combine runs on 64 threads; replay reads H from the (overwritten) P slot.
// Arithmetic is operation-identical to the old p1/comb/p2 (bit-exact).
// ---------------------------------------------------------------------------
__global__ __launch_bounds__(256) void scan_fused(const u16* __restrict__ xb16,
                                                  const float* __restrict__ proj,
                                                  const float* __restrict__ par,
                                                  u16* __restrict__ y) {
    const int tid = threadIdx.x;
    const int h2 = tid & 1;
    const int dsub = (tid >> 1) & 3;
    const int c = tid >> 3;
    const int d = blockIdx.x * 4 + dsub;
    const int b = blockIdx.z;
    const int nb = h2 * 8;

    __shared__ float Pl[CCH][4][17];
    __shared__ float Sl[CCH][4][17];

    float Aneg[8];
#pragma unroll
    for (int n = 0; n < 8; ++n) Aneg[n] = -__expf(par[P_ALOG + d * 16 + nb + n]);
    const float dtw = par[P_DTW + d], dtb = par[P_DTB + d];
    const float Dp = par[P_DPAR + d];

    const size_t row0 = (size_t)b * 1024 + (size_t)c * CT;

    // ---- phase 1: per-chunk P (prod dA) and S (chunk-local h from 0) ----
    {
        float hl[8] = {}, P[8];
#pragma unroll
        for (int n = 0; n < 8; ++n) P[n] = 1.f;
        float xv = bf2f(xb16[row0 * 2048 + d]);
        for (int i = 0; i < CT; ++i) {
            const float xv_next = (i + 1 < CT) ? bf2f(xb16[(row0 + i + 1) * 2048 + d]) : 0.f;
            const size_t pb = (row0 + i) * PSTRIDE;
            const float dtin = proj[pb];
            const float4 q0 = *(const float4*)&proj[pb + nb + 0];
            const float4 q1 = *(const float4*)&proj[pb + nb + 4];
            const float4 q2 = *(const float4*)&proj[pb + nb + 8];
            const float Bv[8] = {q0.y, q0.z, q0.w, q1.x, q1.y, q1.z, q1.w, q2.x};
            const float darg = fmaf(dtin, dtw, dtb);
            const float dt = (darg > 20.f) ? darg : __logf(1.f + __expf(darg));
            const float xdt = xv * dt;
#pragma unroll
            for (int n = 0; n < 8; ++n) {
                const float dA = __expf(dt * Aneg[n]);
                P[n] *= dA;
                hl[n] = fmaf(dA, hl[n], xdt * Bv[n]);
            }
            xv = xv_next;
        }
#pragma unroll
        for (int n = 0; n < 8; ++n) {
            Pl[c][dsub][nb + n] = P[n];
            Sl[c][dsub][nb + n] = hl[n];
        }
    }
    __syncthreads();

    // ---- phase 2: serial combine over chunks; Pl slot becomes H (pre-state) ----
    if (tid < 64) {
        const int dd = tid >> 4, n = tid & 15;
        float hh = 0.f;
#pragma unroll
        for (int cc = 0; cc < CCH; ++cc) {
            const float p = Pl[cc][dd][n];
            const float s = Sl[cc][dd][n];
            Pl[cc][dd][n] = hh;
            hh = fmaf(p, hh, s);
        }
    }
    __syncthreads();

    // ---- phase 3: replay from true initial state, emit y (bf16) ----
    {
        float hl[8];
#pragma unroll
        for (int n = 0; n < 8; ++n) hl[n] = Pl[c][dsub][nb + n];
        float xv = bf2f(xb16[row0 * 2048 + d]);
        for (int i = 0; i < CT; ++i) {
            const float xv_next = (i + 1 < CT) ? bf2f(xb16[(row0 + i + 1) * 2048 + d]) : 0.f;
            const size_t pb = (row0 + i) * PSTRIDE;
            const float dtin = proj[pb];
            const float4 q0 = *(const float4*)&proj[pb + nb + 0];
            const float4 q1 = *(const float4*)&proj[pb + nb + 4];
            const float4 q2 = *(const float4*)&proj[pb + nb + 8];
            const float4 r0 = *(const float4*)&proj[pb + 16 + nb + 0];
            const float4 r1 = *(const float4*)&proj[pb + 16 + nb + 4];
            const float4 r2 = *(const float4*)&proj[pb + 16 + nb + 8];
            const float Bv[8] = {q0.y, q0.z, q0.w, q1.x, q1.y, q1.z, q1.w, q2.x};
            const float Cv[8] = {r0.y, r0.z, r0.w, r1.x, r1.y, r1.z, r1.w, r2.x};
            const float darg = fmaf(dtin, dtw, dtb);
            const float dt = (darg > 20.f) ? darg : __logf(1.f + __expf(darg));
            const float xdt = xv * dt;
            float acc = 0.f;
#pragma unroll
            for (int n = 0; n < 8; ++n) {
                const float dA = __expf(dt * Aneg[n]);
                hl[n] = fmaf(dA, hl[n], xdt * Bv[n]);
                acc = fmaf(hl[n], Cv[n], acc);
            }
            acc += __shfl_xor(acc, 1);
            if (!h2)
                y[(row0 + i) * 2048 + d] = f2bf(fmaf(xv, Dp, acc));
            xv = xv_next;
        }
    }
}

// ---------------------------------------------------------------------------
// LayerNorm over D_INNER + *silu(z); vectorized 8-wide contiguous per thread.
// ---------------------------------------------------------------------------
__global__ __launch_bounds__(256) void ln_silu(const u16* __restrict__ y,
                                               const u16* __restrict__ xz,
                                               const float* __restrict__ par,
                                               u16* __restrict__ yn) {
    const int row = blockIdx.x;
    const int tid = threadIdx.x;
    const int lane = tid & 63, wave = tid >> 6;
    const int d0 = tid * 8;
    const ushort8 vy = *(const ushort8*)&y[(size_t)row * 2048 + d0];
    float v[8];
    float s = 0.f, s2 = 0.f;
#pragma unroll
    for (int i = 0; i < 8; ++i) {
        v[i] = bf2f(vy[i]);
        s += v[i];
        s2 = fmaf(v[i], v[i], s2);
    }
    s += __shfl_xor(s, 1); s2 += __shfl_xor(s2, 1);
    s += __shfl_xor(s, 2); s2 += __shfl_xor(s2, 2);
    s += __shfl_xor(s, 4); s2 += __shfl_xor(s2, 4);
    s += __shfl_xor(s, 8); s2 += __shfl_xor(s2, 8);
    s += __shfl_xor(s, 16); s2 += __shfl_xor(s2, 16);
    s += __shfl_xor(s, 32); s2 += __shfl_xor(s2, 32);
    __shared__ float rs[4], rs2[4];
    if (lane == 0) { rs[wave] = s; rs2[wave] = s2; }
    __syncthreads();
    const float ts = rs[0] + rs[1] + rs[2] + rs[3];
    const float ts2 = rs2[0] + rs2[1] + rs2[2] + rs2[3];
    const float mu = ts * (1.f / 2048.f);
    const float var = ts2 * (1.f / 2048.f) - mu * mu;
    const float rstd = rsqrtf(var + 1e-5f);

    const ushort8 vz = *(const ushort8*)&xz[(size_t)row * 4096 + 2048 + d0];
    float g[8], bb[8];
    {
        const float4 g0 = *(const float4*)&par[P_LNG + d0];
        const float4 g1 = *(const float4*)&par[P_LNG + d0 + 4];
        g[0] = g0.x; g[1] = g0.y; g[2] = g0.z; g[3] = g0.w;
        g[4] = g1.x; g[5] = g1.y; g[6] = g1.z; g[7] = g1.w;
        const float4 b0 = *(const float4*)&par[P_LNB + d0];
        const float4 b1 = *(const float4*)&par[P_LNB + d0 + 4];
        bb[0] = b0.x; bb[1] = b0.y; bb[2] = b0.z; bb[3] = b0.w;
        bb[4] = b1.x; bb[5] = b1.y; bb[6] = b1.z; bb[7] = b1.w;
    }
    u16 o[8];
#pragma unroll
    for (int i = 0; i < 8; ++i) {
        float t = (v[i] - mu) * rstd * g[i] + bb[i];
        const float z = bf2f(vz[i]);
        t *= z / (1.f + __expf(-z));
        o[i] = f2bf(t);
    }
    *(uint4*)&yn[(size_t)row * 2048 + d0] = *(uint4*)o;
}

// ---------------------------------------------------------------------------
extern "C" void kernel_launch(void* const* d_in, const int* in_sizes, int n_in,
                              void* d_out, int out_size, void* d_ws, size_t ws_size,
                              hipStream_t stream) {
    const void* x         = d_in[0];   // (2,1024,1024) fp32
    const void* in_proj_w = d_in[1];
    const void* conv_w    = d_in[2];
    const void* conv_b    = d_in[3];
    const void* x_proj_w  = d_in[4];
    const void* A_log     = d_in[5];
    const void* D_param   = d_in[6];
    const void* dt_w      = d_in[7];
    const void* dt_b      = d_in[8];
    const void* out_w     = d_in[9];
    const void* ln_g      = d_in[10];
    const void* ln_b      = d_in[11];
    const u16* dp = (const u16*)D_param;

    // workspace layout
    float* cpar = (float*)d_ws;              // 53,248 f32
    u16* cx     = (u16*)(cpar + P_TOTAL);    // 2,097,152 u16 (4 MB)
    u16* cw1    = cx + 2097152;              // 4,194,304 u16 (8 MB)
    u16* cwo    = cw1 + 4194304;             // 2,097,152 u16 (4 MB)
    u16* xz     = cwo + 2097152;             // 8,388,608 u16 (16 MB)
    u16* xb16   = xz + 8388608;              // 4,194,304 u16 (8 MB)
    u16* y      = xb16 + 4194304;            // 4,194,304 u16 (8 MB)
    u16* wpad   = y + 4194304;               // 262,144 u16   (0.5 MB)
    float* proj = (float*)(wpad + 262144);   // 2048*128 f32  (1 MB)
    float* PS   = proj + 262144;             // (region kept; unused now)
    float* H    = PS + 2 * CHUNKTOT;         // (region kept; unused now)
    float* gpart = H + CHUNKTOT;             // 2*2048*1024 f32 (16 MB)
    // overlays:
    float* xpart = gpart;                    // 16*2048*128 f32 (16 MB) — dead before gemm3
    u16* yn      = xb16;                     // xb16 dead after scan_fused

    // raise dynamic-LDS cap for the 144 KiB GEMM (host-side, graph-safe)
    static bool attrSet = false;
    if (!attrSet) {
        hipFuncSetAttribute(reinterpret_cast<const void*>(&gemm8<0>),
                            hipFuncAttributeMaxDynamicSharedMemorySize, 147456);
        hipFuncSetAttribute(reinterpret_cast<const void*>(&gemm8<1>),
                            hipFuncAttributeMaxDynamicSharedMemorySize, 147456);
        attrSet = true;
    }

    // 0. canonicalize params + convert GEMM operands to bf16
    ParamPtrs pp;
    pp.p[0] = conv_w; pp.p[1] = conv_b; pp.p[2] = A_log; pp.p[3] = D_param;
    pp.p[4] = dt_w;   pp.p[5] = dt_b;   pp.p[6] = ln_g;  pp.p[7] = ln_b;
    canon_all<<<8656, 256, 0, stream>>>(pp, cpar, x, in_proj_w, out_w, cx,
                                        x_proj_w, wpad, dp);

    // 1. in_proj: xz = x @ in_proj_w^T   (M=2048, N=4096, K=1024), bf16 out
    gemm8<0><<<dim3(16, 16, 1), 512, 147456, stream>>>(cx, cw1, xz,
                                                       2048, 4096, 1024, 1024, 1024);
    // 2. causal conv4 + silu -> bf16
    conv_silu<<<2048, 256, 0, stream>>>(xz, cpar, xb16);
    // 3. x_proj GEMM, split-K 16 (full grid): xpart[z] = xb16 @ wpad^T (K seg 128)
    gemm_bt<1><<<dim3(16, 1, 16), 256, 0, stream>>>(xb16, wpad, xpart, 2048, 128, 128, 2048, 2048);
    reduce_parts<<<256, 256, 0, stream>>>(xpart, proj, 65536, 16);
    // 4. fused chunked scan (p1 + combine + p2 in one kernel)
    scan_fused<<<dim3(512, 1, 2), 256, 0, stream>>>(xb16, proj, cpar, y);
    // 5. layernorm + silu(z) gate (yn overlays xb16)
    ln_silu<<<2048, 256, 0, stream>>>(y, xz, cpar, yn);
    // 6. out proj, split-K 2x: gpart[z] = yn @ out_w^T (K seg 1024), then reduce
    gemm8<1><<<dim3(16, 4, 2), 512, 147456, stream>>>(yn, cwo, gpart,
                                                      2048, 1024, 1024, 2048, 2048);
    reduce_parts<<<2048, 256, 0, stream>>>(gpart, (float*)d_out, 524288, 2);
}